// Round 1
// baseline (2346.049 us; speedup 1.0000x reference)
//
#include <hip/hip_runtime.h>
#include <hip/hip_bf16.h>

// Problem constants
// N = B*H*W = 16384 tokens, C = D = 512, M = 100 memory slots, QKV = 300
#define NTOK 16384
#define DDIM 512
#define MMEM 100
#define HWSZ 4096
#define QKVW 300

#define MICRO_FMA(a, b, acc)                          \
  acc[0][0] = fmaf(a.x, b.x, acc[0][0]);              \
  acc[0][1] = fmaf(a.x, b.y, acc[0][1]);              \
  acc[0][2] = fmaf(a.x, b.z, acc[0][2]);              \
  acc[0][3] = fmaf(a.x, b.w, acc[0][3]);              \
  acc[1][0] = fmaf(a.y, b.x, acc[1][0]);              \
  acc[1][1] = fmaf(a.y, b.y, acc[1][1]);              \
  acc[1][2] = fmaf(a.y, b.z, acc[1][2]);              \
  acc[1][3] = fmaf(a.y, b.w, acc[1][3]);              \
  acc[2][0] = fmaf(a.z, b.x, acc[2][0]);              \
  acc[2][1] = fmaf(a.z, b.y, acc[2][1]);              \
  acc[2][2] = fmaf(a.z, b.z, acc[2][2]);              \
  acc[2][3] = fmaf(a.z, b.w, acc[2][3]);              \
  acc[3][0] = fmaf(a.w, b.x, acc[3][0]);              \
  acc[3][1] = fmaf(a.w, b.y, acc[3][1]);              \
  acc[3][2] = fmaf(a.w, b.z, acc[3][2]);              \
  acc[3][3] = fmaf(a.w, b.w, acc[3][3]);

// ---------------------------------------------------------------------------
// K1a: per-token inverse L2 norm of fea rows (token n reads C=512 strided)
__global__ __launch_bounds__(256) void rownorm_k(const float* __restrict__ fea,
                                                 float* __restrict__ invn) {
  int n = blockIdx.x * 256 + threadIdx.x;            // 16384
  int b = n >> 12, hw = n & 4095;
  const float* p = fea + (size_t)b * DDIM * HWSZ + hw;
  float ss = 0.f;
  for (int c = 0; c < DDIM; ++c) { float v = p[(size_t)c * HWSZ]; ss += v * v; }
  invn[n] = 1.f / fmaxf(sqrtf(ss), 1e-12f);
}

// K1b: qn[n, c] = fea[b, c, hw] * invn[n]   (32x32 LDS transpose)
__global__ void make_qn_k(const float* __restrict__ fea,
                          const float* __restrict__ invn,
                          float* __restrict__ qn) {
  __shared__ float tile[32][33];
  int b = blockIdx.z, hw0 = blockIdx.x * 32, c0 = blockIdx.y * 32;
  int tx = threadIdx.x, ty = threadIdx.y;
  const float* src = fea + ((size_t)b * DDIM + c0) * HWSZ + hw0;
#pragma unroll
  for (int i = 0; i < 32; i += 8)
    tile[ty + i][tx] = src[(size_t)(ty + i) * HWSZ + tx];
  __syncthreads();
#pragma unroll
  for (int i = 0; i < 32; i += 8) {
    int n = b * HWSZ + hw0 + ty + i;
    qn[(size_t)n * DDIM + c0 + tx] = tile[tx][ty + i] * invn[n];
  }
}

// ---------------------------------------------------------------------------
// Generic tiled f32 GEMM: C = A(MxK) @ B(KxN) [+ bias], row-major, guarded.
__global__ __launch_bounds__(256) void gemm_f32(
    const float* __restrict__ A, const float* __restrict__ B,
    const float* __restrict__ bias, float* __restrict__ C,
    int M, int N, int K) {
  __shared__ float As[32][68];
  __shared__ float Bs[32][68];
  const int tid = threadIdx.x;
  const int tx = tid & 15, ty = tid >> 4;
  const int row0 = blockIdx.y * 64, col0 = blockIdx.x * 64;
  float acc[4][4] = {};
  for (int k0 = 0; k0 < K; k0 += 32) {
    __syncthreads();
#pragma unroll
    for (int i = 0; i < 8; ++i) {       // A tile 64x32, coalesced along k
      int m = i * 8 + (tid >> 5), kk = tid & 31;
      int r = row0 + m, k = k0 + kk;
      float v = (r < M && k < K) ? A[(size_t)r * K + k] : 0.f;
      As[kk][m] = v;
    }
#pragma unroll
    for (int i = 0; i < 8; ++i) {       // B tile 32x64, coalesced along n
      int kk = i * 4 + (tid >> 6), n = tid & 63;
      int k = k0 + kk, c = col0 + n;
      float v = (k < K && c < N) ? B[(size_t)k * N + c] : 0.f;
      Bs[kk][n] = v;
    }
    __syncthreads();
#pragma unroll
    for (int kk = 0; kk < 32; ++kk) {
      float4 a = *(const float4*)&As[kk][ty * 4];
      float4 b = *(const float4*)&Bs[kk][tx * 4];
      MICRO_FMA(a, b, acc)
    }
  }
#pragma unroll
  for (int u = 0; u < 4; ++u) {
    int r = row0 + ty * 4 + u;
    if (r >= M) continue;
#pragma unroll
    for (int v = 0; v < 4; ++v) {
      int c = col0 + tx * 4 + v;
      if (c >= N) continue;
      float val = acc[u][v];
      if (bias) val += bias[c];
      C[(size_t)r * N + c] = val;
    }
  }
}

// Split-K GEMM with atomic accumulation (C must be pre-zeroed).
__global__ __launch_bounds__(256) void gemm_splitk_f32(
    const float* __restrict__ A, const float* __restrict__ B,
    float* __restrict__ C, int M, int N, int K, int KC) {
  __shared__ float As[32][68];
  __shared__ float Bs[32][68];
  const int tid = threadIdx.x;
  const int tx = tid & 15, ty = tid >> 4;
  const int row0 = blockIdx.y * 64, col0 = blockIdx.x * 64;
  const int kbeg = blockIdx.z * KC;
  const int kend = min(kbeg + KC, K);
  float acc[4][4] = {};
  for (int k0 = kbeg; k0 < kend; k0 += 32) {
    __syncthreads();
#pragma unroll
    for (int i = 0; i < 8; ++i) {
      int m = i * 8 + (tid >> 5), kk = tid & 31;
      int r = row0 + m, k = k0 + kk;
      float v = (r < M && k < kend) ? A[(size_t)r * K + k] : 0.f;
      As[kk][m] = v;
    }
#pragma unroll
    for (int i = 0; i < 8; ++i) {
      int kk = i * 4 + (tid >> 6), n = tid & 63;
      int k = k0 + kk, c = col0 + n;
      float v = (k < kend && c < N) ? B[(size_t)k * N + c] : 0.f;
      Bs[kk][n] = v;
    }
    __syncthreads();
#pragma unroll
    for (int kk = 0; kk < 32; ++kk) {
      float4 a = *(const float4*)&As[kk][ty * 4];
      float4 b = *(const float4*)&Bs[kk][tx * 4];
      MICRO_FMA(a, b, acc)
    }
  }
#pragma unroll
  for (int u = 0; u < 4; ++u) {
    int r = row0 + ty * 4 + u;
    if (r >= M) continue;
#pragma unroll
    for (int v = 0; v < 4; ++v) {
      int c = col0 + tx * 4 + v;
      if (c >= N) continue;
      atomicAdd(&C[(size_t)r * N + c], acc[u][v]);
    }
  }
}

// C[M1,M2] += A^T @ B over a K-chunk.  A:(K x M1), B:(K x M2) row-major.
__global__ __launch_bounds__(256) void atb_f32(
    const float* __restrict__ A, const float* __restrict__ B,
    float* __restrict__ C, int M1, int M2, int K, int KC) {
  __shared__ float As[32][68];
  __shared__ float Bs[32][68];
  const int tid = threadIdx.x;
  const int tx = tid & 15, ty = tid >> 4;
  const int row0 = blockIdx.y * 64, col0 = blockIdx.x * 64;
  const int kbeg = blockIdx.z * KC;
  const int kend = min(kbeg + KC, K);
  float acc[4][4] = {};
  for (int k0 = kbeg; k0 < kend; k0 += 32) {
    __syncthreads();
#pragma unroll
    for (int i = 0; i < 8; ++i) {       // A tile: 32k x 64m, coalesced along m
      int kk = i * 4 + (tid >> 6), m = tid & 63;
      float v = (k0 + kk < kend && row0 + m < M1)
                    ? A[(size_t)(k0 + kk) * M1 + row0 + m] : 0.f;
      As[kk][m] = v;
    }
#pragma unroll
    for (int i = 0; i < 8; ++i) {
      int kk = i * 4 + (tid >> 6), n = tid & 63;
      float v = (k0 + kk < kend && col0 + n < M2)
                    ? B[(size_t)(k0 + kk) * M2 + col0 + n] : 0.f;
      Bs[kk][n] = v;
    }
    __syncthreads();
#pragma unroll
    for (int kk = 0; kk < 32; ++kk) {
      float4 a = *(const float4*)&As[kk][ty * 4];
      float4 b = *(const float4*)&Bs[kk][tx * 4];
      MICRO_FMA(a, b, acc)
    }
  }
#pragma unroll
  for (int u = 0; u < 4; ++u) {
    int r = row0 + ty * 4 + u;
    if (r >= M1) continue;
#pragma unroll
    for (int v = 0; v < 4; ++v) {
      int c = col0 + tx * 4 + v;
      if (c >= M2) continue;
      atomicAdd(&C[(size_t)r * M2 + c], acc[u][v]);
    }
  }
}

// ---------------------------------------------------------------------------
// Row softmax, row length = 100 (one wave per row; 4 rows per 256-thread block)
__global__ __launch_bounds__(256) void softmax100_k(float* __restrict__ x, int nrows) {
  int wid = threadIdx.x >> 6;
  int lane = threadIdx.x & 63;
  int row = blockIdx.x * 4 + wid;
  if (row >= nrows) return;
  float* xr = x + (size_t)row * MMEM;
  float v0 = xr[lane];
  bool has1 = (lane + 64) < MMEM;
  float v1 = has1 ? xr[lane + 64] : -3.4e38f;
  float m = fmaxf(v0, v1);
#pragma unroll
  for (int o = 32; o; o >>= 1) m = fmaxf(m, __shfl_xor(m, o, 64));
  float e0 = expf(v0 - m);
  float e1 = has1 ? expf(v1 - m) : 0.f;
  float s = e0 + e1;
#pragma unroll
  for (int o = 32; o; o >>= 1) s += __shfl_xor(s, o, 64);
  float inv = 1.f / s;
  xr[lane] = e0 * inv;
  if (has1) xr[lane + 64] = e1 * inv;
}

// Column sum of A (nrows x 512), split over row chunks of 512, atomic.
__global__ __launch_bounds__(512) void colsum_k(const float* __restrict__ A,
                                                float* __restrict__ out) {
  int d = threadIdx.x;
  int r0 = blockIdx.x * 512;
  float a = 0.f;
  for (int r = 0; r < 512; ++r) a += A[(size_t)(r0 + r) * DDIM + d];
  atomicAdd(&out[d], a);
}

// ip4sum[f] += sum over 128 flat rows of S_flat[r] * rel_w_flat[r, f]
__global__ __launch_bounds__(256) void ip4sum_k(const float* __restrict__ S,
                                                const float* __restrict__ rel_w,
                                                float* __restrict__ out) {
  __shared__ float sv[128];
  int r0 = blockIdx.x * 128;
  int tid = threadIdx.x;
  if (tid < 128) sv[tid] = S[r0 + tid];
  __syncthreads();
  float a0 = 0.f, a1 = 0.f;
  for (int r = 0; r < 128; ++r) {
    const float* row = rel_w + (size_t)(r0 + r) * DDIM;
    float s = sv[r];
    a0 = fmaf(s, row[tid], a0);
    a1 = fmaf(s, row[tid + 256], a1);
  }
  atomicAdd(&out[tid], a0);
  atomicAdd(&out[tid + 256], a1);
}

// item[d,f] += item_w[d,f] + ip4sum[d]*ip2sum[f]   (item already holds ip1^T ip1)
__global__ __launch_bounds__(256) void assemble_item_k(
    float* __restrict__ item, const float* __restrict__ item_w,
    const float* __restrict__ s4, const float* __restrict__ s2) {
  int idx = blockIdx.x * 256 + threadIdx.x;  // 262144
  int d = idx >> 9, f = idx & 511;
  item[idx] += item_w[idx] + s4[d] * s2[f];
}

// LayerNorm over rows of length 300 with eps = 512 (faithful quirk)
__global__ __launch_bounds__(256) void ln300_k(const float* __restrict__ x,
                                               const float* __restrict__ g,
                                               const float* __restrict__ bb,
                                               float* __restrict__ y) {
  __shared__ float r1[4], r2[4];
  int row = blockIdx.x, tid = threadIdx.x;
  const float* xr = x + (size_t)row * QKVW;
  float v1 = xr[tid];                       // tid < 256 < 300 always valid
  float v2 = (tid + 256 < QKVW) ? xr[tid + 256] : 0.f;
  float s = v1 + v2, q = v1 * v1 + v2 * v2;
#pragma unroll
  for (int o = 32; o; o >>= 1) { s += __shfl_xor(s, o, 64); q += __shfl_xor(q, o, 64); }
  if ((tid & 63) == 0) { r1[tid >> 6] = s; r2[tid >> 6] = q; }
  __syncthreads();
  s = r1[0] + r1[1] + r1[2] + r1[3];
  q = r2[0] + r2[1] + r2[2] + r2[3];
  float mean = s * (1.f / 300.f);
  float var = q * (1.f / 300.f) - mean * mean;
  float inv = rsqrtf(var + 512.0f);
  float* yr = y + (size_t)row * QKVW;
  yr[tid] = (v1 - mean) * inv * g[tid] + bb[tid];
  if (tid + 256 < QKVW)
    yr[tid + 256] = (v2 - mean) * inv * g[tid + 256] + bb[tid + 256];
}

// q/k/v (M x D) row-major from qkv_ln (D x 300)
__global__ __launch_bounds__(256) void split_qkv_k(const float* __restrict__ y,
                                                   float* __restrict__ qm,
                                                   float* __restrict__ km,
                                                   float* __restrict__ vm) {
  int idx = blockIdx.x * 256 + threadIdx.x;  // 51200
  int d = idx / MMEM, i = idx % MMEM;
  const float* row = y + (size_t)d * QKVW;
  qm[(size_t)i * DDIM + d] = row[i];
  km[(size_t)i * DDIM + d] = row[MMEM + i];
  vm[(size_t)i * DDIM + d] = row[2 * MMEM + i];
}

// rel_new[i,d,f] = rel_w[i,d,f] + sum_j tanh(q[i,d]*k[j,d]) * v[j,f]
__global__ __launch_bounds__(256) void rel0_k(
    const float* __restrict__ qm, const float* __restrict__ km,
    const float* __restrict__ vm, const float* __restrict__ rel_w,
    float* __restrict__ relnew) {
  const int i = blockIdx.y;
  const int d0 = blockIdx.x * 64;
  __shared__ float ts[100][68];
  __shared__ float vs[100][68];
  __shared__ float qv[64];
  const int tid = threadIdx.x;
  const int tx = tid & 15, ty = tid >> 4;
  if (tid < 64) qv[tid] = qm[(size_t)i * DDIM + d0 + tid];
  __syncthreads();
  for (int idx = tid; idx < 6400; idx += 256) {
    int j = idx >> 6, dd = idx & 63;
    ts[j][dd] = tanhf(qv[dd] * km[(size_t)j * DDIM + d0 + dd]);
  }
  for (int f0 = 0; f0 < DDIM; f0 += 64) {
    __syncthreads();
    for (int idx = tid; idx < 6400; idx += 256) {
      int j = idx >> 6, ff = idx & 63;
      vs[j][ff] = vm[(size_t)j * DDIM + f0 + ff];
    }
    __syncthreads();
    float acc[4][4] = {};
    for (int j = 0; j < 100; ++j) {
      float4 a = *(const float4*)&ts[j][ty * 4];
      float4 b = *(const float4*)&vs[j][tx * 4];
      MICRO_FMA(a, b, acc)
    }
#pragma unroll
    for (int u = 0; u < 4; ++u) {
      size_t off = ((size_t)i * DDIM + d0 + ty * 4 + u) * DDIM + f0 + tx * 4;
      float4 rw = *(const float4*)&rel_w[off];
      float4 o;
      o.x = rw.x + acc[u][0]; o.y = rw.y + acc[u][1];
      o.z = rw.z + acc[u][2]; o.w = rw.w + acc[u][3];
      *(float4*)&relnew[off] = o;
    }
  }
}

// mn[i,:] = l2norm(memacc[i,:] + br1); also write mn^T
__global__ __launch_bounds__(256) void mn_k(const float* __restrict__ macc,
                                            const float* __restrict__ br1,
                                            float* __restrict__ mn,
                                            float* __restrict__ mnT) {
  __shared__ float r1[4];
  int i = blockIdx.x, tid = threadIdx.x;
  float v0 = macc[(size_t)i * DDIM + tid] + br1[tid];
  float v1 = macc[(size_t)i * DDIM + tid + 256] + br1[tid + 256];
  float q = v0 * v0 + v1 * v1;
#pragma unroll
  for (int o = 32; o; o >>= 1) q += __shfl_xor(q, o, 64);
  if ((tid & 63) == 0) r1[tid >> 6] = q;
  __syncthreads();
  q = r1[0] + r1[1] + r1[2] + r1[3];
  float inv = 1.f / fmaxf(sqrtf(q), 1e-12f);
  float a = v0 * inv, b = v1 * inv;
  mn[(size_t)i * DDIM + tid] = a;
  mn[(size_t)i * DDIM + tid + 256] = b;
  mnT[(size_t)tid * MMEM + i] = a;
  mnT[(size_t)(tid + 256) * MMEM + i] = b;
}

// out[:, :512] = fea  (float4 copy)
__global__ __launch_bounds__(256) void copy_fea_k(const float* __restrict__ fea,
                                                  float* __restrict__ out) {
  size_t i = (size_t)blockIdx.x * 256 + threadIdx.x;   // 2,097,152 float4
  float4 v = ((const float4*)fea)[i];
  size_t b = i >> 19;            // 524288 float4 per batch
  size_t rem = i & 524287;
  ((float4*)(out + b * 4194304))[rem] = v;
}

// out[b, 512+c, hw] = mf[b*4096+hw, c]   (32x32 LDS transpose)
__global__ void write_mf_k(const float* __restrict__ mf, float* __restrict__ out) {
  __shared__ float tile[32][33];
  int b = blockIdx.z, hw0 = blockIdx.x * 32, c0 = blockIdx.y * 32;
  int tx = threadIdx.x, ty = threadIdx.y;
#pragma unroll
  for (int i = 0; i < 32; i += 8)
    tile[ty + i][tx] = mf[((size_t)b * HWSZ + hw0 + ty + i) * DDIM + c0 + tx];
  __syncthreads();
#pragma unroll
  for (int i = 0; i < 32; i += 8)
    out[(size_t)b * 4194304 + (size_t)(512 + c0 + ty + i) * HWSZ + hw0 + tx] =
        tile[tx][ty + i];
}

// ---------------------------------------------------------------------------
extern "C" void kernel_launch(void* const* d_in, const int* in_sizes, int n_in,
                              void* d_out, int out_size, void* d_ws, size_t ws_size,
                              hipStream_t stream) {
  (void)in_sizes; (void)n_in; (void)out_size; (void)ws_size;
  const float* fea    = (const float*)d_in[0];
  const float* item_w = (const float*)d_in[1];
  const float* rel_w  = (const float*)d_in[2];
  const float* W1     = (const float*)d_in[3];
  const float* b1     = (const float*)d_in[4];
  const float* W2     = (const float*)d_in[5];
  const float* b2     = (const float*)d_in[6];
  const float* W3     = (const float*)d_in[7];
  const float* b3     = (const float*)d_in[8];
  const float* Wqkv   = (const float*)d_in[9];
  const float* bqkv   = (const float*)d_in[10];
  const float* ln_g   = (const float*)d_in[11];
  const float* ln_b   = (const float*)d_in[12];
  const float* Wr1    = (const float*)d_in[13];
  const float* br1    = (const float*)d_in[14];
  float* out = (float*)d_out;
  float* ws = (float*)d_ws;

  // Workspace layout (floats). Peak ~142 MB.
  float* qn  = ws;                                  // 16384*512
  float* big = qn + (size_t)NTOK * DDIM;            // 26,214,400-float region
  float* ip1 = big;                                 //   16384*512
  float* ip2 = big + (size_t)NTOK * DDIM;           //   16384*512
  float* ip3 = big + (size_t)2 * NTOK * DDIM;       //   16384*100
  float* relnew = big;                              //   100*512*512 (reuse)
  float* addr = big;                                //   16384*100   (reuse)
  float* mf   = big + (size_t)NTOK * MMEM;          //   16384*512   (reuse)
  float* smallr = big + (size_t)26214400;
  float* S      = smallr;                           // 51200   (zeroed)
  float* ip4sum = S + 51200;                        // 512     (zeroed)
  float* ip2sum = ip4sum + 512;                     // 512     (zeroed)
  float* item   = ip2sum + 512;                     // 262144  (zeroed)
  float* memacc = item + 262144;                    // 51200   (zeroed)
  float* qkv    = memacc + 51200;                   // 153600
  float* qkvln  = qkv + 153600;                     // 153600
  float* qm     = qkvln + 153600;                   // 51200
  float* km     = qm + 51200;                       // 51200
  float* vm     = km + 51200;                       // 51200
  float* mnb    = vm + 51200;                       // 51200
  float* mnT    = mnb + 51200;                      // 51200
  float* invn   = mnT + 51200;                      // 16384

  // zero the atomic-accumulation targets (contiguous span) — every call
  hipMemsetAsync(S, 0, (size_t)(51200 + 512 + 512 + 262144 + 51200) * sizeof(float),
                 stream);

  // 1) qn = l2norm(rows of fea^T)
  rownorm_k<<<64, 256, 0, stream>>>(fea, invn);
  make_qn_k<<<dim3(128, 16, 4), dim3(32, 8), 0, stream>>>(fea, invn, qn);

  // 2) ip1, ip2, ip3
  gemm_f32<<<dim3(8, 256), 256, 0, stream>>>(qn, W1, b1, ip1, NTOK, DDIM, DDIM);
  gemm_f32<<<dim3(8, 256), 256, 0, stream>>>(qn, W2, b2, ip2, NTOK, DDIM, DDIM);
  gemm_f32<<<dim3(2, 256), 256, 0, stream>>>(qn, W3, b3, ip3, NTOK, MMEM, DDIM);
  softmax100_k<<<4096, 256, 0, stream>>>(ip3, NTOK);

  // 3) S = ip3^T @ ip2 ; item (part 1) = ip1^T @ ip1 ; ip2sum ; ip4sum
  atb_f32<<<dim3(8, 2, 16), 256, 0, stream>>>(ip3, ip2, S, MMEM, DDIM, NTOK, 1024);
  atb_f32<<<dim3(8, 8, 8), 256, 0, stream>>>(ip1, ip1, item, DDIM, DDIM, NTOK, 2048);
  colsum_k<<<32, 512, 0, stream>>>(ip2, ip2sum);
  ip4sum_k<<<400, 256, 0, stream>>>(S, rel_w, ip4sum);

  // 4) item = ip1^T ip1 + item_w + outer(ip4sum, ip2sum)
  assemble_item_k<<<1024, 256, 0, stream>>>(item, item_w, ip4sum, ip2sum);

  // 5) qkv GEMM + LayerNorm(eps=512) + split to q/k/v (M x D)
  gemm_f32<<<dim3(5, 8), 256, 0, stream>>>(item, Wqkv, bqkv, qkv, DDIM, QKVW, DDIM);
  ln300_k<<<512, 256, 0, stream>>>(qkv, ln_g, ln_b, qkvln);
  split_qkv_k<<<200, 256, 0, stream>>>(qkvln, qm, km, vm);

  // 6) rel_new = rel_w + einsum(tanh(q⊙k), v)
  rel0_k<<<dim3(8, MMEM), 256, 0, stream>>>(qm, km, vm, rel_w, relnew);

  // 7) memory = rel_new_flat @ Wr1 (+ br1 folded into mn_k)
  gemm_splitk_f32<<<dim3(8, 2, 64), 256, 0, stream>>>(relnew, Wr1, memacc,
                                                      MMEM, DDIM, 262144, 4096);
  mn_k<<<MMEM, 256, 0, stream>>>(memacc, br1, mnb, mnT);

  // 8) addr = softmax(qn @ mn^T); mf = addr @ mn
  gemm_f32<<<dim3(2, 256), 256, 0, stream>>>(qn, mnT, nullptr, addr, NTOK, MMEM, DDIM);
  softmax100_k<<<4096, 256, 0, stream>>>(addr, NTOK);
  gemm_f32<<<dim3(8, 256), 256, 0, stream>>>(addr, mnb, nullptr, mf, NTOK, DDIM, MMEM);

  // 9) output assembly: concat([fea, mf^T], channel axis)
  copy_fea_k<<<8192, 256, 0, stream>>>(fea, out);
  write_mf_k<<<dim3(128, 16, 4), dim3(32, 8), 0, stream>>>(mf, out);
}

// Round 2
// 1664.380 us; speedup vs baseline: 1.4096x; 1.4096x over previous
//
#include <hip/hip_runtime.h>
#include <hip/hip_bf16.h>

// Problem constants
// N = B*H*W = 16384 tokens, C = D = 512, M = 100 memory slots, QKV = 300
#define NTOK 16384
#define DDIM 512
#define MMEM 100
#define HWSZ 4096
#define QKVW 300

typedef __attribute__((ext_vector_type(8))) short short8v;   // 8 bf16 (4 VGPRs)
typedef __attribute__((ext_vector_type(4))) float f32x4;

__device__ __forceinline__ unsigned short f2bf(float x) {
  union { float f; unsigned int u; } v; v.f = x;
  unsigned int r = v.u + 0x7fff + ((v.u >> 16) & 1);   // round-to-nearest-even
  return (unsigned short)(r >> 16);
}

#define MICRO_FMA(a, b, acc)                          \
  acc[0][0] = fmaf(a.x, b.x, acc[0][0]);              \
  acc[0][1] = fmaf(a.x, b.y, acc[0][1]);              \
  acc[0][2] = fmaf(a.x, b.z, acc[0][2]);              \
  acc[0][3] = fmaf(a.x, b.w, acc[0][3]);              \
  acc[1][0] = fmaf(a.y, b.x, acc[1][0]);              \
  acc[1][1] = fmaf(a.y, b.y, acc[1][1]);              \
  acc[1][2] = fmaf(a.y, b.z, acc[1][2]);              \
  acc[1][3] = fmaf(a.y, b.w, acc[1][3]);              \
  acc[2][0] = fmaf(a.z, b.x, acc[2][0]);              \
  acc[2][1] = fmaf(a.z, b.y, acc[2][1]);              \
  acc[2][2] = fmaf(a.z, b.z, acc[2][2]);              \
  acc[2][3] = fmaf(a.z, b.w, acc[2][3]);              \
  acc[3][0] = fmaf(a.w, b.x, acc[3][0]);              \
  acc[3][1] = fmaf(a.w, b.y, acc[3][1]);              \
  acc[3][2] = fmaf(a.w, b.z, acc[3][2]);              \
  acc[3][3] = fmaf(a.w, b.w, acc[3][3]);

// ---------------------------------------------------------------------------
// K1a: per-token inverse L2 norm of fea rows (token n reads C=512 strided)
__global__ __launch_bounds__(256) void rownorm_k(const float* __restrict__ fea,
                                                 float* __restrict__ invn) {
  int n = blockIdx.x * 256 + threadIdx.x;            // 16384
  int b = n >> 12, hw = n & 4095;
  const float* p = fea + (size_t)b * DDIM * HWSZ + hw;
  float ss = 0.f;
  for (int c = 0; c < DDIM; ++c) { float v = p[(size_t)c * HWSZ]; ss += v * v; }
  invn[n] = 1.f / fmaxf(sqrtf(ss), 1e-12f);
}

// K1b: qn[n, c] = fea[b, c, hw] * invn[n]   (32x32 LDS transpose)
__global__ void make_qn_k(const float* __restrict__ fea,
                          const float* __restrict__ invn,
                          float* __restrict__ qn) {
  __shared__ float tile[32][33];
  int b = blockIdx.z, hw0 = blockIdx.x * 32, c0 = blockIdx.y * 32;
  int tx = threadIdx.x, ty = threadIdx.y;
  const float* src = fea + ((size_t)b * DDIM + c0) * HWSZ + hw0;
#pragma unroll
  for (int i = 0; i < 32; i += 8)
    tile[ty + i][tx] = src[(size_t)(ty + i) * HWSZ + tx];
  __syncthreads();
#pragma unroll
  for (int i = 0; i < 32; i += 8) {
    int n = b * HWSZ + hw0 + ty + i;
    qn[(size_t)n * DDIM + c0 + tx] = tile[tx][ty + i] * invn[n];
  }
}

// ---------------------------------------------------------------------------
// Generic tiled f32 GEMM: C = A(MxK) @ B(KxN) [+ bias], row-major, guarded.
__global__ __launch_bounds__(256) void gemm_f32(
    const float* __restrict__ A, const float* __restrict__ B,
    const float* __restrict__ bias, float* __restrict__ C,
    int M, int N, int K) {
  __shared__ float As[32][68];
  __shared__ float Bs[32][68];
  const int tid = threadIdx.x;
  const int tx = tid & 15, ty = tid >> 4;
  const int row0 = blockIdx.y * 64, col0 = blockIdx.x * 64;
  float acc[4][4] = {};
  for (int k0 = 0; k0 < K; k0 += 32) {
    __syncthreads();
#pragma unroll
    for (int i = 0; i < 8; ++i) {       // A tile 64x32, coalesced along k
      int m = i * 8 + (tid >> 5), kk = tid & 31;
      int r = row0 + m, k = k0 + kk;
      float v = (r < M && k < K) ? A[(size_t)r * K + k] : 0.f;
      As[kk][m] = v;
    }
#pragma unroll
    for (int i = 0; i < 8; ++i) {       // B tile 32x64, coalesced along n
      int kk = i * 4 + (tid >> 6), n = tid & 63;
      int k = k0 + kk, c = col0 + n;
      float v = (k < K && c < N) ? B[(size_t)k * N + c] : 0.f;
      Bs[kk][n] = v;
    }
    __syncthreads();
#pragma unroll
    for (int kk = 0; kk < 32; ++kk) {
      float4 a = *(const float4*)&As[kk][ty * 4];
      float4 b = *(const float4*)&Bs[kk][tx * 4];
      MICRO_FMA(a, b, acc)
    }
  }
#pragma unroll
  for (int u = 0; u < 4; ++u) {
    int r = row0 + ty * 4 + u;
    if (r >= M) continue;
#pragma unroll
    for (int v = 0; v < 4; ++v) {
      int c = col0 + tx * 4 + v;
      if (c >= N) continue;
      float val = acc[u][v];
      if (bias) val += bias[c];
      C[(size_t)r * N + c] = val;
    }
  }
}

// C[M1,M2] += A^T @ B over a K-chunk.  A:(K x M1), B:(K x M2) row-major.
__global__ __launch_bounds__(256) void atb_f32(
    const float* __restrict__ A, const float* __restrict__ B,
    float* __restrict__ C, int M1, int M2, int K, int KC) {
  __shared__ float As[32][68];
  __shared__ float Bs[32][68];
  const int tid = threadIdx.x;
  const int tx = tid & 15, ty = tid >> 4;
  const int row0 = blockIdx.y * 64, col0 = blockIdx.x * 64;
  const int kbeg = blockIdx.z * KC;
  const int kend = min(kbeg + KC, K);
  float acc[4][4] = {};
  for (int k0 = kbeg; k0 < kend; k0 += 32) {
    __syncthreads();
#pragma unroll
    for (int i = 0; i < 8; ++i) {       // A tile: 32k x 64m, coalesced along m
      int kk = i * 4 + (tid >> 6), m = tid & 63;
      float v = (k0 + kk < kend && row0 + m < M1)
                    ? A[(size_t)(k0 + kk) * M1 + row0 + m] : 0.f;
      As[kk][m] = v;
    }
#pragma unroll
    for (int i = 0; i < 8; ++i) {
      int kk = i * 4 + (tid >> 6), n = tid & 63;
      float v = (k0 + kk < kend && col0 + n < M2)
                    ? B[(size_t)(k0 + kk) * M2 + col0 + n] : 0.f;
      Bs[kk][n] = v;
    }
    __syncthreads();
#pragma unroll
    for (int kk = 0; kk < 32; ++kk) {
      float4 a = *(const float4*)&As[kk][ty * 4];
      float4 b = *(const float4*)&Bs[kk][tx * 4];
      MICRO_FMA(a, b, acc)
    }
  }
#pragma unroll
  for (int u = 0; u < 4; ++u) {
    int r = row0 + ty * 4 + u;
    if (r >= M1) continue;
#pragma unroll
    for (int v = 0; v < 4; ++v) {
      int c = col0 + tx * 4 + v;
      if (c >= M2) continue;
      atomicAdd(&C[(size_t)r * M2 + c], acc[u][v]);
    }
  }
}

// ---------------------------------------------------------------------------
// memgemm: partial[z] = A(100x262144, f32) chunk_z @ B(262144x512, f32),
// bf16 MFMA with on-the-fly conversion. Grid: 256 chunks (KC=1024), 512 thr.
// Wave w owns a 128x64 output panel (8 m-tiles x 4 n-tiles of 16x16).
#define MGK 262144
#define MGKC 1024
#define MGCHUNK 256
__global__ __launch_bounds__(512) void memgemm_k(const float* __restrict__ Ag,
                                                 const float* __restrict__ Bg,
                                                 float* __restrict__ partial) {
  __shared__ unsigned short As[128][40];   // [m][k] bf16, pad to 40 (80B rows)
  __shared__ unsigned short Bs[32][520];   // [k][n] bf16, pad to 520 (1040B rows)
  const int tid = threadIdx.x;
  const int l = tid & 63;
  const int w = tid >> 6;                  // 0..7
  const int n0 = w * 64;
  const int kbeg = blockIdx.x * MGKC;
  // staging roles
  const int arow = tid >> 2, akq = tid & 3;     // A: row, 8-k group
  const int bkrow = tid >> 4, bnq = tid & 15;   // B: k-row, 32-n group
  const int l15 = l & 15, lhi = l >> 4;

  f32x4 acc[8][4] = {};

  for (int t = 0; t < MGKC / 32; ++t) {
    const int kb = kbeg + t * 32;
    // -- global loads (f32), issued before the barrier to overlap compute
    float4 av0, av1;
    if (arow < MMEM) {
      const float* ap = Ag + (size_t)arow * MGK + kb + akq * 8;
      av0 = *(const float4*)ap;
      av1 = *(const float4*)(ap + 4);
    } else {
      av0 = make_float4(0.f, 0.f, 0.f, 0.f); av1 = av0;
    }
    float4 bv[8];
    const float* bp = Bg + (size_t)(kb + bkrow) * DDIM + bnq * 32;
#pragma unroll
    for (int u = 0; u < 8; ++u) bv[u] = *(const float4*)(bp + u * 4);

    __syncthreads();   // previous tile's LDS reads done
    // -- convert + LDS write
    {
      short8v pa;
      pa[0] = (short)f2bf(av0.x); pa[1] = (short)f2bf(av0.y);
      pa[2] = (short)f2bf(av0.z); pa[3] = (short)f2bf(av0.w);
      pa[4] = (short)f2bf(av1.x); pa[5] = (short)f2bf(av1.y);
      pa[6] = (short)f2bf(av1.z); pa[7] = (short)f2bf(av1.w);
      *(short8v*)&As[arow][akq * 8] = pa;
    }
#pragma unroll
    for (int u = 0; u < 4; ++u) {
      short8v pb;
      pb[0] = (short)f2bf(bv[2 * u].x);     pb[1] = (short)f2bf(bv[2 * u].y);
      pb[2] = (short)f2bf(bv[2 * u].z);     pb[3] = (short)f2bf(bv[2 * u].w);
      pb[4] = (short)f2bf(bv[2 * u + 1].x); pb[5] = (short)f2bf(bv[2 * u + 1].y);
      pb[6] = (short)f2bf(bv[2 * u + 1].z); pb[7] = (short)f2bf(bv[2 * u + 1].w);
      *(short8v*)&Bs[bkrow][bnq * 32 + u * 8] = pb;
    }
    __syncthreads();
    // -- fragments + MFMA (one K=32 step per tile)
    short8v afr[8];
#pragma unroll
    for (int mt = 0; mt < 8; ++mt)
      afr[mt] = *(const short8v*)&As[mt * 16 + l15][lhi * 8];
#pragma unroll
    for (int ct = 0; ct < 4; ++ct) {
      union { short8v v; unsigned short u[8]; } bf;
      const int nn = n0 + ct * 16 + l15;
#pragma unroll
      for (int j = 0; j < 8; ++j) bf.u[j] = Bs[lhi * 8 + j][nn];
#pragma unroll
      for (int mt = 0; mt < 8; ++mt)
        acc[mt][ct] = __builtin_amdgcn_mfma_f32_16x16x32_bf16(
            afr[mt], bf.v, acc[mt][ct], 0, 0, 0);
    }
  }

  // -- epilogue: partial write (rows < 100 only)
  float* pw = partial + (size_t)blockIdx.x * (MMEM * DDIM);
#pragma unroll
  for (int mt = 0; mt < 8; ++mt) {
    const int r0 = mt * 16 + lhi * 4;
#pragma unroll
    for (int r = 0; r < 4; ++r) {
      const int row = r0 + r;
      if (row < MMEM) {
#pragma unroll
        for (int ct = 0; ct < 4; ++ct)
          pw[(size_t)row * DDIM + n0 + ct * 16 + l15] = acc[mt][ct][r];
      }
    }
  }
}

// memacc[i] += sum over 64 chunks of partial[z][i]  (grid.y = 4 segments)
__global__ __launch_bounds__(256) void reduce_partials_k(
    const float* __restrict__ p, float* __restrict__ out) {
  int i = blockIdx.x * 256 + threadIdx.x;          // 51200
  int z0 = blockIdx.y * 64;
  float s = 0.f;
  for (int z = 0; z < 64; ++z) s += p[(size_t)(z0 + z) * (MMEM * DDIM) + i];
  atomicAdd(&out[i], s);
}

// ---------------------------------------------------------------------------
// Row softmax, row length = 100 (one wave per row; 4 rows per 256-thread block)
__global__ __launch_bounds__(256) void softmax100_k(float* __restrict__ x, int nrows) {
  int wid = threadIdx.x >> 6;
  int lane = threadIdx.x & 63;
  int row = blockIdx.x * 4 + wid;
  if (row >= nrows) return;
  float* xr = x + (size_t)row * MMEM;
  float v0 = xr[lane];
  bool has1 = (lane + 64) < MMEM;
  float v1 = has1 ? xr[lane + 64] : -3.4e38f;
  float m = fmaxf(v0, v1);
#pragma unroll
  for (int o = 32; o; o >>= 1) m = fmaxf(m, __shfl_xor(m, o, 64));
  float e0 = expf(v0 - m);
  float e1 = has1 ? expf(v1 - m) : 0.f;
  float s = e0 + e1;
#pragma unroll
  for (int o = 32; o; o >>= 1) s += __shfl_xor(s, o, 64);
  float inv = 1.f / s;
  xr[lane] = e0 * inv;
  if (has1) xr[lane + 64] = e1 * inv;
}

// Column sum of A (nrows x 512), split over row chunks of 512, atomic.
__global__ __launch_bounds__(512) void colsum_k(const float* __restrict__ A,
                                                float* __restrict__ out) {
  int d = threadIdx.x;
  int r0 = blockIdx.x * 512;
  float a = 0.f;
  for (int r = 0; r < 512; ++r) a += A[(size_t)(r0 + r) * DDIM + d];
  atomicAdd(&out[d], a);
}

// ip4sum[f] += sum over 128 flat rows of S_flat[r] * rel_w_flat[r, f]
__global__ __launch_bounds__(256) void ip4sum_k(const float* __restrict__ S,
                                                const float* __restrict__ rel_w,
                                                float* __restrict__ out) {
  __shared__ float sv[128];
  int r0 = blockIdx.x * 128;
  int tid = threadIdx.x;
  if (tid < 128) sv[tid] = S[r0 + tid];
  __syncthreads();
  float a0 = 0.f, a1 = 0.f;
  for (int r = 0; r < 128; ++r) {
    const float* row = rel_w + (size_t)(r0 + r) * DDIM;
    float s = sv[r];
    a0 = fmaf(s, row[tid], a0);
    a1 = fmaf(s, row[tid + 256], a1);
  }
  atomicAdd(&out[tid], a0);
  atomicAdd(&out[tid + 256], a1);
}

// item[d,f] += item_w[d,f] + ip4sum[d]*ip2sum[f]   (item already holds ip1^T ip1)
__global__ __launch_bounds__(256) void assemble_item_k(
    float* __restrict__ item, const float* __restrict__ item_w,
    const float* __restrict__ s4, const float* __restrict__ s2) {
  int idx = blockIdx.x * 256 + threadIdx.x;  // 262144
  int d = idx >> 9, f = idx & 511;
  item[idx] += item_w[idx] + s4[d] * s2[f];
}

// LayerNorm over rows of length 300 with eps = 512 (faithful quirk)
__global__ __launch_bounds__(256) void ln300_k(const float* __restrict__ x,
                                               const float* __restrict__ g,
                                               const float* __restrict__ bb,
                                               float* __restrict__ y) {
  __shared__ float r1[4], r2[4];
  int row = blockIdx.x, tid = threadIdx.x;
  const float* xr = x + (size_t)row * QKVW;
  float v1 = xr[tid];
  float v2 = (tid + 256 < QKVW) ? xr[tid + 256] : 0.f;
  float s = v1 + v2, q = v1 * v1 + v2 * v2;
#pragma unroll
  for (int o = 32; o; o >>= 1) { s += __shfl_xor(s, o, 64); q += __shfl_xor(q, o, 64); }
  if ((tid & 63) == 0) { r1[tid >> 6] = s; r2[tid >> 6] = q; }
  __syncthreads();
  s = r1[0] + r1[1] + r1[2] + r1[3];
  q = r2[0] + r2[1] + r2[2] + r2[3];
  float mean = s * (1.f / 300.f);
  float var = q * (1.f / 300.f) - mean * mean;
  float inv = rsqrtf(var + 512.0f);
  float* yr = y + (size_t)row * QKVW;
  yr[tid] = (v1 - mean) * inv * g[tid] + bb[tid];
  if (tid + 256 < QKVW)
    yr[tid + 256] = (v2 - mean) * inv * g[tid + 256] + bb[tid + 256];
}

// q/k/v (M x D) row-major from qkv_ln (D x 300)
__global__ __launch_bounds__(256) void split_qkv_k(const float* __restrict__ y,
                                                   float* __restrict__ qm,
                                                   float* __restrict__ km,
                                                   float* __restrict__ vm) {
  int idx = blockIdx.x * 256 + threadIdx.x;  // 51200
  int d = idx / MMEM, i = idx % MMEM;
  const float* row = y + (size_t)d * QKVW;
  qm[(size_t)i * DDIM + d] = row[i];
  km[(size_t)i * DDIM + d] = row[MMEM + i];
  vm[(size_t)i * DDIM + d] = row[2 * MMEM + i];
}

// rel_new[i,d,f] = rel_w[i,d,f] + sum_j tanh(q[i,d]*k[j,d]) * v[j,f]
__global__ __launch_bounds__(256) void rel0_k(
    const float* __restrict__ qm, const float* __restrict__ km,
    const float* __restrict__ vm, const float* __restrict__ rel_w,
    float* __restrict__ relnew) {
  const int i = blockIdx.y;
  const int d0 = blockIdx.x * 64;
  __shared__ float ts[100][68];
  __shared__ float vs[100][68];
  __shared__ float qv[64];
  const int tid = threadIdx.x;
  const int tx = tid & 15, ty = tid >> 4;
  if (tid < 64) qv[tid] = qm[(size_t)i * DDIM + d0 + tid];
  __syncthreads();
  for (int idx = tid; idx < 6400; idx += 256) {
    int j = idx >> 6, dd = idx & 63;
    ts[j][dd] = tanhf(qv[dd] * km[(size_t)j * DDIM + d0 + dd]);
  }
  for (int f0 = 0; f0 < DDIM; f0 += 64) {
    __syncthreads();
    for (int idx = tid; idx < 6400; idx += 256) {
      int j = idx >> 6, ff = idx & 63;
      vs[j][ff] = vm[(size_t)j * DDIM + f0 + ff];
    }
    __syncthreads();
    float acc[4][4] = {};
    for (int j = 0; j < 100; ++j) {
      float4 a = *(const float4*)&ts[j][ty * 4];
      float4 b = *(const float4*)&vs[j][tx * 4];
      MICRO_FMA(a, b, acc)
    }
#pragma unroll
    for (int u = 0; u < 4; ++u) {
      size_t off = ((size_t)i * DDIM + d0 + ty * 4 + u) * DDIM + f0 + tx * 4;
      float4 rw = *(const float4*)&rel_w[off];
      float4 o;
      o.x = rw.x + acc[u][0]; o.y = rw.y + acc[u][1];
      o.z = rw.z + acc[u][2]; o.w = rw.w + acc[u][3];
      *(float4*)&relnew[off] = o;
    }
  }
}

// mn[i,:] = l2norm(memacc[i,:] + br1); also write mn^T
__global__ __launch_bounds__(256) void mn_k(const float* __restrict__ macc,
                                            const float* __restrict__ br1,
                                            float* __restrict__ mn,
                                            float* __restrict__ mnT) {
  __shared__ float r1[4];
  int i = blockIdx.x, tid = threadIdx.x;
  float v0 = macc[(size_t)i * DDIM + tid] + br1[tid];
  float v1 = macc[(size_t)i * DDIM + tid + 256] + br1[tid + 256];
  float q = v0 * v0 + v1 * v1;
#pragma unroll
  for (int o = 32; o; o >>= 1) q += __shfl_xor(q, o, 64);
  if ((tid & 63) == 0) r1[tid >> 6] = q;
  __syncthreads();
  q = r1[0] + r1[1] + r1[2] + r1[3];
  float inv = 1.f / fmaxf(sqrtf(q), 1e-12f);
  float a = v0 * inv, b = v1 * inv;
  mn[(size_t)i * DDIM + tid] = a;
  mn[(size_t)i * DDIM + tid + 256] = b;
  mnT[(size_t)tid * MMEM + i] = a;
  mnT[(size_t)(tid + 256) * MMEM + i] = b;
}

// out[:, :512] = fea  (float4 copy)
__global__ __launch_bounds__(256) void copy_fea_k(const float* __restrict__ fea,
                                                  float* __restrict__ out) {
  size_t i = (size_t)blockIdx.x * 256 + threadIdx.x;   // 2,097,152 float4
  float4 v = ((const float4*)fea)[i];
  size_t b = i >> 19;            // 524288 float4 per batch
  size_t rem = i & 524287;
  ((float4*)(out + b * 4194304))[rem] = v;
}

// out[b, 512+c, hw] = mf[b*4096+hw, c]   (32x32 LDS transpose)
__global__ void write_mf_k(const float* __restrict__ mf, float* __restrict__ out) {
  __shared__ float tile[32][33];
  int b = blockIdx.z, hw0 = blockIdx.x * 32, c0 = blockIdx.y * 32;
  int tx = threadIdx.x, ty = threadIdx.y;
#pragma unroll
  for (int i = 0; i < 32; i += 8)
    tile[ty + i][tx] = mf[((size_t)b * HWSZ + hw0 + ty + i) * DDIM + c0 + tx];
  __syncthreads();
#pragma unroll
  for (int i = 0; i < 32; i += 8)
    out[(size_t)b * 4194304 + (size_t)(512 + c0 + ty + i) * HWSZ + hw0 + tx] =
        tile[tx][ty + i];
}

// ---------------------------------------------------------------------------
extern "C" void kernel_launch(void* const* d_in, const int* in_sizes, int n_in,
                              void* d_out, int out_size, void* d_ws, size_t ws_size,
                              hipStream_t stream) {
  (void)in_sizes; (void)n_in; (void)out_size; (void)ws_size;
  const float* fea    = (const float*)d_in[0];
  const float* item_w = (const float*)d_in[1];
  const float* rel_w  = (const float*)d_in[2];
  const float* W1     = (const float*)d_in[3];
  const float* b1     = (const float*)d_in[4];
  const float* W2     = (const float*)d_in[5];
  const float* b2     = (const float*)d_in[6];
  const float* W3     = (const float*)d_in[7];
  const float* b3     = (const float*)d_in[8];
  const float* Wqkv   = (const float*)d_in[9];
  const float* bqkv   = (const float*)d_in[10];
  const float* ln_g   = (const float*)d_in[11];
  const float* ln_b   = (const float*)d_in[12];
  const float* Wr1    = (const float*)d_in[13];
  const float* br1    = (const float*)d_in[14];
  float* out = (float*)d_out;
  float* ws = (float*)d_ws;

  // Workspace layout (floats). Peak ~194 MB.
  float* qn  = ws;                                  // 16384*512
  float* big = qn + (size_t)NTOK * DDIM;            // 26,214,400-float region
  float* ip1 = big;                                 //   16384*512
  float* ip2 = big + (size_t)NTOK * DDIM;           //   16384*512
  float* ip3 = big + (size_t)2 * NTOK * DDIM;       //   16384*100
  float* relnew = big;                              //   100*512*512 (reuse)
  float* addr = big;                                //   16384*100   (reuse, after memgemm)
  float* mf   = big + (size_t)NTOK * MMEM;          //   16384*512   (reuse)
  float* smallr = big + (size_t)26214400;
  float* S      = smallr;                           // 51200   (zeroed)
  float* ip4sum = S + 51200;                        // 512     (zeroed)
  float* ip2sum = ip4sum + 512;                     // 512     (zeroed)
  float* item   = ip2sum + 512;                     // 262144  (zeroed)
  float* memacc = item + 262144;                    // 51200   (zeroed)
  float* qkv    = memacc + 51200;                   // 153600
  float* qkvln  = qkv + 153600;                     // 153600
  float* qm     = qkvln + 153600;                   // 51200
  float* km     = qm + 51200;                       // 51200
  float* vm     = km + 51200;                       // 51200
  float* mnb    = vm + 51200;                       // 51200
  float* mnT    = mnb + 51200;                      // 51200
  float* invn   = mnT + 51200;                      // 16384
  float* partial = invn + 16384;                    // 256*51200 (memgemm partials)

  // zero the atomic-accumulation targets (contiguous span) — every call
  hipMemsetAsync(S, 0, (size_t)(51200 + 512 + 512 + 262144 + 51200) * sizeof(float),
                 stream);

  // 1) qn = l2norm(rows of fea^T)
  rownorm_k<<<64, 256, 0, stream>>>(fea, invn);
  make_qn_k<<<dim3(128, 16, 4), dim3(32, 8), 0, stream>>>(fea, invn, qn);

  // 2) ip1, ip2, ip3
  gemm_f32<<<dim3(8, 256), 256, 0, stream>>>(qn, W1, b1, ip1, NTOK, DDIM, DDIM);
  gemm_f32<<<dim3(8, 256), 256, 0, stream>>>(qn, W2, b2, ip2, NTOK, DDIM, DDIM);
  gemm_f32<<<dim3(2, 256), 256, 0, stream>>>(qn, W3, b3, ip3, NTOK, MMEM, DDIM);
  softmax100_k<<<4096, 256, 0, stream>>>(ip3, NTOK);

  // 3) S = ip3^T @ ip2 ; item (part 1) = ip1^T @ ip1 ; ip2sum ; ip4sum
  atb_f32<<<dim3(8, 2, 16), 256, 0, stream>>>(ip3, ip2, S, MMEM, DDIM, NTOK, 1024);
  atb_f32<<<dim3(8, 8, 8), 256, 0, stream>>>(ip1, ip1, item, DDIM, DDIM, NTOK, 2048);
  colsum_k<<<32, 512, 0, stream>>>(ip2, ip2sum);
  ip4sum_k<<<400, 256, 0, stream>>>(S, rel_w, ip4sum);

  // 4) item = ip1^T ip1 + item_w + outer(ip4sum, ip2sum)
  assemble_item_k<<<1024, 256, 0, stream>>>(item, item_w, ip4sum, ip2sum);

  // 5) qkv GEMM + LayerNorm(eps=512) + split to q/k/v (M x D)
  gemm_f32<<<dim3(5, 8), 256, 0, stream>>>(item, Wqkv, bqkv, qkv, DDIM, QKVW, DDIM);
  ln300_k<<<512, 256, 0, stream>>>(qkv, ln_g, ln_b, qkvln);
  split_qkv_k<<<200, 256, 0, stream>>>(qkvln, qm, km, vm);

  // 6) rel_new = rel_w + einsum(tanh(q⊙k), v)
  rel0_k<<<dim3(8, MMEM), 256, 0, stream>>>(qm, km, vm, rel_w, relnew);

  // 7) memory = rel_new_flat @ Wr1 (+ br1 folded into mn_k) — bf16 MFMA
  memgemm_k<<<dim3(MGCHUNK), 512, 0, stream>>>(relnew, Wr1, partial);
  reduce_partials_k<<<dim3(200, 4), 256, 0, stream>>>(partial, memacc);
  mn_k<<<MMEM, 256, 0, stream>>>(memacc, br1, mnb, mnT);

  // 8) addr = softmax(qn @ mn^T); mf = addr @ mn
  gemm_f32<<<dim3(2, 256), 256, 0, stream>>>(qn, mnT, nullptr, addr, NTOK, MMEM, DDIM);
  softmax100_k<<<4096, 256, 0, stream>>>(addr, NTOK);
  gemm_f32<<<dim3(8, 256), 256, 0, stream>>>(addr, mnb, nullptr, mf, NTOK, DDIM, MMEM);

  // 9) output assembly: concat([fea, mf^T], channel axis)
  copy_fea_k<<<8192, 256, 0, stream>>>(fea, out);
  write_mf_k<<<dim3(128, 16, 4), dim3(32, 8), 0, stream>>>(mf, out);
}

// Round 3
// 727.576 us; speedup vs baseline: 3.2245x; 2.2876x over previous
//
#include <hip/hip_runtime.h>
#include <hip/hip_bf16.h>

// Problem constants
#define NTOK 16384
#define DDIM 512
#define MMEM 100
#define HWSZ 4096
#define QKVW 300

typedef __attribute__((ext_vector_type(8))) short short8v;   // 8 bf16
typedef __attribute__((ext_vector_type(4))) short short4v;   // 4 bf16
typedef __attribute__((ext_vector_type(4))) float f32x4;

__device__ __forceinline__ unsigned short f2bf(float x) {
  union { __hip_bfloat16 h; unsigned short u; } cv;
  cv.h = __float2bfloat16(x);
  return cv.u;
}

#define MICRO_FMA(a, b, acc)                          \
  acc[0][0] = fmaf(a.x, b.x, acc[0][0]);              \
  acc[0][1] = fmaf(a.x, b.y, acc[0][1]);              \
  acc[0][2] = fmaf(a.x, b.z, acc[0][2]);              \
  acc[0][3] = fmaf(a.x, b.w, acc[0][3]);              \
  acc[1][0] = fmaf(a.y, b.x, acc[1][0]);              \
  acc[1][1] = fmaf(a.y, b.y, acc[1][1]);              \
  acc[1][2] = fmaf(a.y, b.z, acc[1][2]);              \
  acc[1][3] = fmaf(a.y, b.w, acc[1][3]);              \
  acc[2][0] = fmaf(a.z, b.x, acc[2][0]);              \
  acc[2][1] = fmaf(a.z, b.y, acc[2][1]);              \
  acc[2][2] = fmaf(a.z, b.z, acc[2][2]);              \
  acc[2][3] = fmaf(a.z, b.w, acc[2][3]);              \
  acc[3][0] = fmaf(a.w, b.x, acc[3][0]);              \
  acc[3][1] = fmaf(a.w, b.y, acc[3][1]);              \
  acc[3][2] = fmaf(a.w, b.z, acc[3][2]);              \
  acc[3][3] = fmaf(a.w, b.w, acc[3][3]);

// ---------------------------------------------------------------------------
__global__ __launch_bounds__(256) void rownorm_k(const float* __restrict__ fea,
                                                 float* __restrict__ invn) {
  int n = blockIdx.x * 256 + threadIdx.x;
  int b = n >> 12, hw = n & 4095;
  const float* p = fea + (size_t)b * DDIM * HWSZ + hw;
  float ss = 0.f;
  for (int c = 0; c < DDIM; ++c) { float v = p[(size_t)c * HWSZ]; ss += v * v; }
  invn[n] = 1.f / fmaxf(sqrtf(ss), 1e-12f);
}

__global__ void make_qn_k(const float* __restrict__ fea,
                          const float* __restrict__ invn,
                          float* __restrict__ qn) {
  __shared__ float tile[32][33];
  int b = blockIdx.z, hw0 = blockIdx.x * 32, c0 = blockIdx.y * 32;
  int tx = threadIdx.x, ty = threadIdx.y;
  const float* src = fea + ((size_t)b * DDIM + c0) * HWSZ + hw0;
#pragma unroll
  for (int i = 0; i < 32; i += 8)
    tile[ty + i][tx] = src[(size_t)(ty + i) * HWSZ + tx];
  __syncthreads();
#pragma unroll
  for (int i = 0; i < 32; i += 8) {
    int n = b * HWSZ + hw0 + ty + i;
    qn[(size_t)n * DDIM + c0 + tx] = tile[tx][ty + i] * invn[n];
  }
}

// Generic 32x32 transpose: src (R x C) -> dst (C x R), guarded.
__global__ void transpose_k(const float* __restrict__ src,
                            float* __restrict__ dst, int R, int C) {
  __shared__ float tile[32][33];
  int c0 = blockIdx.x * 32, r0 = blockIdx.y * 32;
  int tx = threadIdx.x, ty = threadIdx.y;
#pragma unroll
  for (int i = 0; i < 32; i += 8) {
    int r = r0 + ty + i, c = c0 + tx;
    if (r < R && c < C) tile[ty + i][tx] = src[(size_t)r * C + c];
  }
  __syncthreads();
#pragma unroll
  for (int i = 0; i < 32; i += 8) {
    int c = c0 + ty + i, r = r0 + tx;
    if (c < C && r < R) dst[(size_t)c * R + r] = tile[tx][ty + i];
  }
}

// ---------------------------------------------------------------------------
// bf16 MFMA GEMM: C(MxN) = A(MxK)@B(KxN) [+bias], f32 in/out, on-the-fly cvt.
// 128x128 tile, BK=32, 256 threads = 4 waves (2x2), each wave 64x64.
// ATOMIC: split-K chunk (blockIdx.z*KC..), atomicAdd into pre-zeroed C.
template<bool ATOMIC>
__global__ __launch_bounds__(256) void gemm_mfma_k(
    const float* __restrict__ A, const float* __restrict__ B,
    const float* __restrict__ bias, float* __restrict__ C,
    int M, int N, int K, int lda, int ldb, int ldc, int KC) {
  __shared__ unsigned short As[128][40];    // [m][k] bf16, row 80B
  __shared__ unsigned short Bs[32][132];    // [k][n] bf16, row 264B (66 words)
  const int tid = threadIdx.x;
  const int l = tid & 63, w = tid >> 6;
  const int l15 = l & 15, lhi = l >> 4;
  const int wm = w >> 1, wn = w & 1;
  const int row0 = blockIdx.y * 128, col0 = blockIdx.x * 128;
  const int kbeg = blockIdx.z * KC;
  const int kend = min(kbeg + KC, K);
  const int am = tid >> 1, akq = (tid & 1) << 4;   // A staging: [am][akq..+15]
  const int bk = tid >> 3, bnq = (tid & 7) << 4;   // B staging: [bk][bnq..+15]
  const int arow = row0 + am;

  f32x4 acc[4][4] = {};

  for (int k0 = kbeg; k0 < kend; k0 += 32) {
    float av[16], bv[16];
    if (arow < M) {
      const float* ap = A + (size_t)arow * lda + k0 + akq;
      if (k0 + akq + 15 < kend) {
#pragma unroll
        for (int u = 0; u < 4; ++u) {
          float4 t4 = *(const float4*)(ap + 4 * u);
          av[4*u] = t4.x; av[4*u+1] = t4.y; av[4*u+2] = t4.z; av[4*u+3] = t4.w;
        }
      } else {
#pragma unroll
        for (int e = 0; e < 16; ++e) av[e] = (k0 + akq + e < kend) ? ap[e] : 0.f;
      }
    } else {
#pragma unroll
      for (int e = 0; e < 16; ++e) av[e] = 0.f;
    }
    {
      const int kk = k0 + bk;
      if (kk < kend) {
        const float* bp = B + (size_t)kk * ldb + col0 + bnq;
        if (col0 + bnq + 15 < N) {
#pragma unroll
          for (int u = 0; u < 4; ++u) {
            float4 t4 = *(const float4*)(bp + 4 * u);
            bv[4*u] = t4.x; bv[4*u+1] = t4.y; bv[4*u+2] = t4.z; bv[4*u+3] = t4.w;
          }
        } else {
#pragma unroll
          for (int e = 0; e < 16; ++e)
            bv[e] = (col0 + bnq + e < N) ? bp[e] : 0.f;
        }
      } else {
#pragma unroll
        for (int e = 0; e < 16; ++e) bv[e] = 0.f;
      }
    }
    __syncthreads();   // previous iteration's LDS reads complete
    {
      short8v p0, p1;
#pragma unroll
      for (int e = 0; e < 8; ++e) p0[e] = (short)f2bf(av[e]);
#pragma unroll
      for (int e = 0; e < 8; ++e) p1[e] = (short)f2bf(av[8 + e]);
      *(short8v*)&As[am][akq] = p0;
      *(short8v*)&As[am][akq + 8] = p1;
    }
#pragma unroll
    for (int u = 0; u < 4; ++u) {
      short4v pb;
#pragma unroll
      for (int e = 0; e < 4; ++e) pb[e] = (short)f2bf(bv[4 * u + e]);
      *(short4v*)&Bs[bk][bnq + 4 * u] = pb;
    }
    __syncthreads();
    short8v af[4];
#pragma unroll
    for (int mt = 0; mt < 4; ++mt)
      af[mt] = *(const short8v*)&As[wm * 64 + mt * 16 + l15][lhi * 8];
#pragma unroll
    for (int ct = 0; ct < 4; ++ct) {
      union { short8v v; unsigned short u[8]; } bf;
      const int nn = wn * 64 + ct * 16 + l15;
#pragma unroll
      for (int j = 0; j < 8; ++j) bf.u[j] = Bs[lhi * 8 + j][nn];
#pragma unroll
      for (int mt = 0; mt < 4; ++mt)
        acc[mt][ct] = __builtin_amdgcn_mfma_f32_16x16x32_bf16(
            af[mt], bf.v, acc[mt][ct], 0, 0, 0);
    }
  }

#pragma unroll
  for (int mt = 0; mt < 4; ++mt) {
    const int rb = row0 + wm * 64 + mt * 16 + lhi * 4;
#pragma unroll
    for (int u = 0; u < 4; ++u) {
      const int r = rb + u;
      if (r >= M) continue;
#pragma unroll
      for (int ct = 0; ct < 4; ++ct) {
        const int c = col0 + wn * 64 + ct * 16 + l15;
        if (c >= N) continue;
        float val = acc[mt][ct][u];
        if (ATOMIC) {
          atomicAdd(&C[(size_t)r * ldc + c], val);
        } else {
          if (bias) val += bias[c];
          C[(size_t)r * ldc + c] = val;
        }
      }
    }
  }
}

// ---------------------------------------------------------------------------
// memgemm: partial[z] = A(100x262144) chunk_z @ B(262144x512), bf16 MFMA.
#define MGK 262144
#define MGKC 1024
#define MGCHUNK 256
__global__ __launch_bounds__(512) void memgemm_k(const float* __restrict__ Ag,
                                                 const float* __restrict__ Bg,
                                                 float* __restrict__ partial) {
  __shared__ unsigned short As[128][40];
  __shared__ unsigned short Bs[32][520];
  const int tid = threadIdx.x;
  const int l = tid & 63;
  const int w = tid >> 6;
  const int n0 = w * 64;
  const int kbeg = blockIdx.x * MGKC;
  const int arow = tid >> 2, akq = tid & 3;
  const int bkrow = tid >> 4, bnq = tid & 15;
  const int l15 = l & 15, lhi = l >> 4;

  f32x4 acc[8][4] = {};

  for (int t = 0; t < MGKC / 32; ++t) {
    const int kb = kbeg + t * 32;
    float4 av0, av1;
    if (arow < MMEM) {
      const float* ap = Ag + (size_t)arow * MGK + kb + akq * 8;
      av0 = *(const float4*)ap;
      av1 = *(const float4*)(ap + 4);
    } else {
      av0 = make_float4(0.f, 0.f, 0.f, 0.f); av1 = av0;
    }
    float4 bv[8];
    const float* bp = Bg + (size_t)(kb + bkrow) * DDIM + bnq * 32;
#pragma unroll
    for (int u = 0; u < 8; ++u) bv[u] = *(const float4*)(bp + u * 4);

    __syncthreads();
    {
      short8v pa;
      pa[0] = (short)f2bf(av0.x); pa[1] = (short)f2bf(av0.y);
      pa[2] = (short)f2bf(av0.z); pa[3] = (short)f2bf(av0.w);
      pa[4] = (short)f2bf(av1.x); pa[5] = (short)f2bf(av1.y);
      pa[6] = (short)f2bf(av1.z); pa[7] = (short)f2bf(av1.w);
      *(short8v*)&As[arow][akq * 8] = pa;
    }
#pragma unroll
    for (int u = 0; u < 4; ++u) {
      short8v pb;
      pb[0] = (short)f2bf(bv[2*u].x);   pb[1] = (short)f2bf(bv[2*u].y);
      pb[2] = (short)f2bf(bv[2*u].z);   pb[3] = (short)f2bf(bv[2*u].w);
      pb[4] = (short)f2bf(bv[2*u+1].x); pb[5] = (short)f2bf(bv[2*u+1].y);
      pb[6] = (short)f2bf(bv[2*u+1].z); pb[7] = (short)f2bf(bv[2*u+1].w);
      *(short8v*)&Bs[bkrow][bnq * 32 + u * 8] = pb;
    }
    __syncthreads();
    short8v afr[8];
#pragma unroll
    for (int mt = 0; mt < 8; ++mt)
      afr[mt] = *(const short8v*)&As[mt * 16 + l15][lhi * 8];
#pragma unroll
    for (int ct = 0; ct < 4; ++ct) {
      union { short8v v; unsigned short u[8]; } bf;
      const int nn = n0 + ct * 16 + l15;
#pragma unroll
      for (int j = 0; j < 8; ++j) bf.u[j] = Bs[lhi * 8 + j][nn];
#pragma unroll
      for (int mt = 0; mt < 8; ++mt)
        acc[mt][ct] = __builtin_amdgcn_mfma_f32_16x16x32_bf16(
            afr[mt], bf.v, acc[mt][ct], 0, 0, 0);
    }
  }

  float* pw = partial + (size_t)blockIdx.x * (MMEM * DDIM);
#pragma unroll
  for (int mt = 0; mt < 8; ++mt) {
    const int r0 = mt * 16 + lhi * 4;
#pragma unroll
    for (int r = 0; r < 4; ++r) {
      const int row = r0 + r;
      if (row < MMEM) {
#pragma unroll
        for (int ct = 0; ct < 4; ++ct)
          pw[(size_t)row * DDIM + n0 + ct * 16 + l15] = acc[mt][ct][r];
      }
    }
  }
}

__global__ __launch_bounds__(256) void reduce_partials_k(
    const float* __restrict__ p, float* __restrict__ out) {
  int i = blockIdx.x * 256 + threadIdx.x;
  int z0 = blockIdx.y * 64;
  float s = 0.f;
  for (int z = 0; z < 64; ++z) s += p[(size_t)(z0 + z) * (MMEM * DDIM) + i];
  atomicAdd(&out[i], s);
}

// ---------------------------------------------------------------------------
// Row softmax over first MMEM cols of rows with leading dim ld.
__global__ __launch_bounds__(256) void softmax100_k(float* __restrict__ x,
                                                    int nrows, int ld) {
  int wid = threadIdx.x >> 6;
  int lane = threadIdx.x & 63;
  int row = blockIdx.x * 4 + wid;
  if (row >= nrows) return;
  float* xr = x + (size_t)row * ld;
  float v0 = xr[lane];
  bool has1 = (lane + 64) < MMEM;
  float v1 = has1 ? xr[lane + 64] : -3.4e38f;
  float m = fmaxf(v0, v1);
#pragma unroll
  for (int o = 32; o; o >>= 1) m = fmaxf(m, __shfl_xor(m, o, 64));
  float e0 = expf(v0 - m);
  float e1 = has1 ? expf(v1 - m) : 0.f;
  float s = e0 + e1;
#pragma unroll
  for (int o = 32; o; o >>= 1) s += __shfl_xor(s, o, 64);
  float inv = 1.f / s;
  xr[lane] = e0 * inv;
  if (has1) xr[lane + 64] = e1 * inv;
}

__global__ __launch_bounds__(512) void colsum_k(const float* __restrict__ A,
                                                float* __restrict__ out) {
  int d = threadIdx.x;
  int r0 = blockIdx.x * 512;
  float a = 0.f;
  for (int r = 0; r < 512; ++r) a += A[(size_t)(r0 + r) * DDIM + d];
  atomicAdd(&out[d], a);
}

__global__ __launch_bounds__(256) void ip4sum_k(const float* __restrict__ S,
                                                const float* __restrict__ rel_w,
                                                float* __restrict__ out) {
  __shared__ float sv[128];
  int r0 = blockIdx.x * 128;
  int tid = threadIdx.x;
  if (tid < 128) sv[tid] = S[r0 + tid];
  __syncthreads();
  float a0 = 0.f, a1 = 0.f;
  for (int r = 0; r < 128; ++r) {
    const float* row = rel_w + (size_t)(r0 + r) * DDIM;
    float s = sv[r];
    a0 = fmaf(s, row[tid], a0);
    a1 = fmaf(s, row[tid + 256], a1);
  }
  atomicAdd(&out[tid], a0);
  atomicAdd(&out[tid + 256], a1);
}

__global__ __launch_bounds__(256) void assemble_item_k(
    float* __restrict__ item, const float* __restrict__ item_w,
    const float* __restrict__ s4, const float* __restrict__ s2) {
  int idx = blockIdx.x * 256 + threadIdx.x;
  int d = idx >> 9, f = idx & 511;
  item[idx] += item_w[idx] + s4[d] * s2[f];
}

__global__ __launch_bounds__(256) void ln300_k(const float* __restrict__ x,
                                               const float* __restrict__ g,
                                               const float* __restrict__ bb,
                                               float* __restrict__ y) {
  __shared__ float r1[4], r2[4];
  int row = blockIdx.x, tid = threadIdx.x;
  const float* xr = x + (size_t)row * QKVW;
  float v1 = xr[tid];
  float v2 = (tid + 256 < QKVW) ? xr[tid + 256] : 0.f;
  float s = v1 + v2, q = v1 * v1 + v2 * v2;
#pragma unroll
  for (int o = 32; o; o >>= 1) { s += __shfl_xor(s, o, 64); q += __shfl_xor(q, o, 64); }
  if ((tid & 63) == 0) { r1[tid >> 6] = s; r2[tid >> 6] = q; }
  __syncthreads();
  s = r1[0] + r1[1] + r1[2] + r1[3];
  q = r2[0] + r2[1] + r2[2] + r2[3];
  float mean = s * (1.f / 300.f);
  float var = q * (1.f / 300.f) - mean * mean;
  float inv = rsqrtf(var + 512.0f);
  float* yr = y + (size_t)row * QKVW;
  yr[tid] = (v1 - mean) * inv * g[tid] + bb[tid];
  if (tid + 256 < QKVW)
    yr[tid + 256] = (v2 - mean) * inv * g[tid + 256] + bb[tid + 256];
}

__global__ __launch_bounds__(256) void split_qkv_k(const float* __restrict__ y,
                                                   float* __restrict__ qm,
                                                   float* __restrict__ km,
                                                   float* __restrict__ vm) {
  int idx = blockIdx.x * 256 + threadIdx.x;
  int d = idx / MMEM, i = idx % MMEM;
  const float* row = y + (size_t)d * QKVW;
  qm[(size_t)i * DDIM + d] = row[i];
  km[(size_t)i * DDIM + d] = row[MMEM + i];
  vm[(size_t)i * DDIM + d] = row[2 * MMEM + i];
}

__global__ __launch_bounds__(256) void rel0_k(
    const float* __restrict__ qm, const float* __restrict__ km,
    const float* __restrict__ vm, const float* __restrict__ rel_w,
    float* __restrict__ relnew) {
  const int i = blockIdx.y;
  const int d0 = blockIdx.x * 64;
  __shared__ float ts[100][68];
  __shared__ float vs[100][68];
  __shared__ float qv[64];
  const int tid = threadIdx.x;
  const int tx = tid & 15, ty = tid >> 4;
  if (tid < 64) qv[tid] = qm[(size_t)i * DDIM + d0 + tid];
  __syncthreads();
  for (int idx = tid; idx < 6400; idx += 256) {
    int j = idx >> 6, dd = idx & 63;
    ts[j][dd] = tanhf(qv[dd] * km[(size_t)j * DDIM + d0 + dd]);
  }
  for (int f0 = 0; f0 < DDIM; f0 += 64) {
    __syncthreads();
    for (int idx = tid; idx < 6400; idx += 256) {
      int j = idx >> 6, ff = idx & 63;
      vs[j][ff] = vm[(size_t)j * DDIM + f0 + ff];
    }
    __syncthreads();
    float acc[4][4] = {};
    for (int j = 0; j < 100; ++j) {
      float4 a = *(const float4*)&ts[j][ty * 4];
      float4 b = *(const float4*)&vs[j][tx * 4];
      MICRO_FMA(a, b, acc)
    }
#pragma unroll
    for (int u = 0; u < 4; ++u) {
      size_t off = ((size_t)i * DDIM + d0 + ty * 4 + u) * DDIM + f0 + tx * 4;
      float4 rw = *(const float4*)&rel_w[off];
      float4 o;
      o.x = rw.x + acc[u][0]; o.y = rw.y + acc[u][1];
      o.z = rw.z + acc[u][2]; o.w = rw.w + acc[u][3];
      *(float4*)&relnew[off] = o;
    }
  }
}

__global__ __launch_bounds__(256) void mn_k(const float* __restrict__ macc,
                                            const float* __restrict__ br1,
                                            float* __restrict__ mn,
                                            float* __restrict__ mnT) {
  __shared__ float r1[4];
  int i = blockIdx.x, tid = threadIdx.x;
  float v0 = macc[(size_t)i * DDIM + tid] + br1[tid];
  float v1 = macc[(size_t)i * DDIM + tid + 256] + br1[tid + 256];
  float q = v0 * v0 + v1 * v1;
#pragma unroll
  for (int o = 32; o; o >>= 1) q += __shfl_xor(q, o, 64);
  if ((tid & 63) == 0) r1[tid >> 6] = q;
  __syncthreads();
  q = r1[0] + r1[1] + r1[2] + r1[3];
  float inv = 1.f / fmaxf(sqrtf(q), 1e-12f);
  float a = v0 * inv, b = v1 * inv;
  mn[(size_t)i * DDIM + tid] = a;
  mn[(size_t)i * DDIM + tid + 256] = b;
  mnT[(size_t)tid * MMEM + i] = a;
  mnT[(size_t)(tid + 256) * MMEM + i] = b;
}

__global__ __launch_bounds__(256) void copy_fea_k(const float* __restrict__ fea,
                                                  float* __restrict__ out) {
  size_t i = (size_t)blockIdx.x * 256 + threadIdx.x;
  float4 v = ((const float4*)fea)[i];
  size_t b = i >> 19;
  size_t rem = i & 524287;
  ((float4*)(out + b * 4194304))[rem] = v;
}

__global__ void write_mf_k(const float* __restrict__ mf, float* __restrict__ out) {
  __shared__ float tile[32][33];
  int b = blockIdx.z, hw0 = blockIdx.x * 32, c0 = blockIdx.y * 32;
  int tx = threadIdx.x, ty = threadIdx.y;
#pragma unroll
  for (int i = 0; i < 32; i += 8)
    tile[ty + i][tx] = mf[((size_t)b * HWSZ + hw0 + ty + i) * DDIM + c0 + tx];
  __syncthreads();
#pragma unroll
  for (int i = 0; i < 32; i += 8)
    out[(size_t)b * 4194304 + (size_t)(512 + c0 + ty + i) * HWSZ + hw0 + tx] =
        tile[tx][ty + i];
}

// ---------------------------------------------------------------------------
extern "C" void kernel_launch(void* const* d_in, const int* in_sizes, int n_in,
                              void* d_out, int out_size, void* d_ws, size_t ws_size,
                              hipStream_t stream) {
  (void)in_sizes; (void)n_in; (void)out_size; (void)ws_size;
  const float* fea    = (const float*)d_in[0];
  const float* item_w = (const float*)d_in[1];
  const float* rel_w  = (const float*)d_in[2];
  const float* W1     = (const float*)d_in[3];
  const float* b1     = (const float*)d_in[4];
  const float* W2     = (const float*)d_in[5];
  const float* b2     = (const float*)d_in[6];
  const float* W3     = (const float*)d_in[7];
  const float* b3     = (const float*)d_in[8];
  const float* Wqkv   = (const float*)d_in[9];
  const float* bqkv   = (const float*)d_in[10];
  const float* ln_g   = (const float*)d_in[11];
  const float* ln_b   = (const float*)d_in[12];
  const float* Wr1    = (const float*)d_in[13];
  const float* br1    = (const float*)d_in[14];
  float* out = (float*)d_out;
  float* ws = (float*)d_ws;

  // Disjoint workspace layout (floats), ~384 MB total.
  float* qn     = ws;                         // 8,388,608
  float* ip1    = qn     + 8388608;           // 8,388,608
  float* ip2    = ip1    + 8388608;           // 8,388,608
  float* ip3    = ip2    + 8388608;           // 1,638,400 (ld=100)
  float* ip1T   = ip3    + 1638400;           // 8,388,608 (512 x 16384)
  float* ip3T   = ip1T   + 8388608;           // 1,638,400 (100 x 16384)
  float* relnew = ip3T   + 1638400;           // 26,214,400
  float* addr   = relnew + 26214400;          // 2,097,152 (ld=128)
  float* mf     = addr   + 2097152;           // 8,388,608
  float* partial= mf     + 8388608;           // 13,107,200
  float* S      = partial+ 13107200;          // 51,200  (zeroed)
  float* ip4sum = S      + 51200;             // 512     (zeroed)
  float* ip2sum = ip4sum + 512;               // 512     (zeroed)
  float* item   = ip2sum + 512;               // 262,144 (zeroed)
  float* memacc = item   + 262144;            // 51,200  (zeroed)
  float* qkv    = memacc + 51200;             // 153,600
  float* qkvln  = qkv    + 153600;            // 153,600
  float* qm     = qkvln  + 153600;            // 51,200
  float* km     = qm     + 51200;             // 51,200
  float* vm     = km     + 51200;             // 51,200
  float* mnb    = vm     + 51200;             // 51,200
  float* mnT    = mnb    + 51200;             // 51,200
  float* invn   = mnT    + 51200;             // 16,384

  hipMemsetAsync(S, 0, (size_t)(51200 + 512 + 512 + 262144 + 51200) * sizeof(float),
                 stream);

  // 1) qn = l2norm(tokens of fea)
  rownorm_k<<<64, 256, 0, stream>>>(fea, invn);
  make_qn_k<<<dim3(128, 16, 4), dim3(32, 8), 0, stream>>>(fea, invn, qn);

  // 2) ip1/ip2/ip3 (bf16 MFMA) + softmax + transposes
  gemm_mfma_k<false><<<dim3(4, 128), 256, 0, stream>>>(
      qn, W1, b1, ip1, NTOK, DDIM, DDIM, DDIM, DDIM, DDIM, DDIM);
  gemm_mfma_k<false><<<dim3(4, 128), 256, 0, stream>>>(
      qn, W2, b2, ip2, NTOK, DDIM, DDIM, DDIM, DDIM, DDIM, DDIM);
  gemm_mfma_k<false><<<dim3(1, 128), 256, 0, stream>>>(
      qn, W3, b3, ip3, NTOK, MMEM, DDIM, DDIM, MMEM, MMEM, DDIM);
  softmax100_k<<<4096, 256, 0, stream>>>(ip3, NTOK, MMEM);
  transpose_k<<<dim3(16, 512), dim3(32, 8), 0, stream>>>(ip1, ip1T, NTOK, DDIM);
  transpose_k<<<dim3(4, 512), dim3(32, 8), 0, stream>>>(ip3, ip3T, NTOK, MMEM);

  // 3) item1 = ip1T@ip1 (split-K), S = ip3T@ip2 (split-K), colsum, ip4sum
  gemm_mfma_k<true><<<dim3(4, 4, 16), 256, 0, stream>>>(
      ip1T, ip1, nullptr, item, DDIM, DDIM, NTOK, NTOK, DDIM, DDIM, 1024);
  gemm_mfma_k<true><<<dim3(4, 1, 64), 256, 0, stream>>>(
      ip3T, ip2, nullptr, S, MMEM, DDIM, NTOK, NTOK, DDIM, DDIM, 256);
  colsum_k<<<32, 512, 0, stream>>>(ip2, ip2sum);
  ip4sum_k<<<400, 256, 0, stream>>>(S, rel_w, ip4sum);

  // 4) item += item_w + outer(ip4sum, ip2sum)
  assemble_item_k<<<1024, 256, 0, stream>>>(item, item_w, ip4sum, ip2sum);

  // 5) qkv = item@Wqkv + bqkv; LN(eps=512); split
  gemm_mfma_k<false><<<dim3(3, 4), 256, 0, stream>>>(
      item, Wqkv, bqkv, qkv, DDIM, QKVW, DDIM, DDIM, QKVW, QKVW, DDIM);
  ln300_k<<<512, 256, 0, stream>>>(qkv, ln_g, ln_b, qkvln);
  split_qkv_k<<<200, 256, 0, stream>>>(qkvln, qm, km, vm);

  // 6) rel_new = rel_w + einsum(tanh(q*k), v)
  rel0_k<<<dim3(8, MMEM), 256, 0, stream>>>(qm, km, vm, rel_w, relnew);

  // 7) memory = rel_new_flat @ Wr1 (bf16 MFMA, split-K partials)
  memgemm_k<<<dim3(MGCHUNK), 512, 0, stream>>>(relnew, Wr1, partial);
  reduce_partials_k<<<dim3(200, 4), 256, 0, stream>>>(partial, memacc);
  mn_k<<<MMEM, 256, 0, stream>>>(memacc, br1, mnb, mnT);

  // 8) addr = softmax(qn@mnT); mf = addr@mnb
  gemm_mfma_k<false><<<dim3(1, 128), 256, 0, stream>>>(
      qn, mnT, nullptr, addr, NTOK, MMEM, DDIM, DDIM, MMEM, 128, DDIM);
  softmax100_k<<<4096, 256, 0, stream>>>(addr, NTOK, 128);
  gemm_mfma_k<false><<<dim3(4, 128), 256, 0, stream>>>(
      addr, mnb, nullptr, mf, NTOK, DDIM, MMEM, 128, DDIM, DDIM, MMEM);

  // 9) output: concat([fea, mf^T], channel axis)
  copy_fea_k<<<8192, 256, 0, stream>>>(fea, out);
  write_mf_k<<<dim3(128, 16, 4), dim3(32, 8), 0, stream>>>(mf, out);
}

// Round 4
// 683.939 us; speedup vs baseline: 3.4302x; 1.0638x over previous
//
#include <hip/hip_runtime.h>
#include <hip/hip_bf16.h>

// Problem constants
#define NTOK 16384
#define DDIM 512
#define MMEM 100
#define HWSZ 4096
#define QKVW 300

typedef __attribute__((ext_vector_type(8))) short short8v;   // 8 bf16
typedef __attribute__((ext_vector_type(4))) short short4v;   // 4 bf16
typedef __attribute__((ext_vector_type(4))) float f32x4;

__device__ __forceinline__ unsigned short f2bf(float x) {
  union { __hip_bfloat16 h; unsigned short u; } cv;
  cv.h = __float2bfloat16(x);
  return cv.u;
}

// ---------------------------------------------------------------------------
__global__ __launch_bounds__(256) void rownorm_k(const float* __restrict__ fea,
                                                 float* __restrict__ invn) {
  int n = blockIdx.x * 256 + threadIdx.x;
  int b = n >> 12, hw = n & 4095;
  const float* p = fea + (size_t)b * DDIM * HWSZ + hw;
  float ss = 0.f;
  for (int c = 0; c < DDIM; ++c) { float v = p[(size_t)c * HWSZ]; ss += v * v; }
  invn[n] = 1.f / fmaxf(sqrtf(ss), 1e-12f);
}

// qn[n, c] = fea[b, c, hw] * invn[n]; also copies fea into out[:, :512, :, :]
__global__ void make_qn_k(const float* __restrict__ fea,
                          const float* __restrict__ invn,
                          float* __restrict__ qn,
                          float* __restrict__ out) {
  __shared__ float tile[32][33];
  int b = blockIdx.z, hw0 = blockIdx.x * 32, c0 = blockIdx.y * 32;
  int tx = threadIdx.x, ty = threadIdx.y;
  const float* src = fea + ((size_t)b * DDIM + c0) * HWSZ + hw0;
  float* dst = out + (size_t)b * 4194304 + (size_t)c0 * HWSZ + hw0;
#pragma unroll
  for (int i = 0; i < 32; i += 8) {
    float v = src[(size_t)(ty + i) * HWSZ + tx];
    tile[ty + i][tx] = v;
    dst[(size_t)(ty + i) * HWSZ + tx] = v;      // fused fea copy
  }
  __syncthreads();
#pragma unroll
  for (int i = 0; i < 32; i += 8) {
    int n = b * HWSZ + hw0 + ty + i;
    qn[(size_t)n * DDIM + c0 + tx] = tile[tx][ty + i] * invn[n];
  }
}

// ---------------------------------------------------------------------------
// bf16 MFMA GEMM: C(MxN) = A(MxK)@B(KxN) [+bias], f32 in/out, on-the-fly cvt.
// 128x128 tile, BK=32, 256 threads = 4 waves (2x2), each wave 64x64.
template<bool ATOMIC>
__global__ __launch_bounds__(256) void gemm_mfma_k(
    const float* __restrict__ A, const float* __restrict__ B,
    const float* __restrict__ bias, float* __restrict__ C,
    int M, int N, int K, int lda, int ldb, int ldc, int KC) {
  __shared__ unsigned short As[128][40];
  __shared__ unsigned short Bs[32][132];
  const int tid = threadIdx.x;
  const int l = tid & 63, w = tid >> 6;
  const int l15 = l & 15, lhi = l >> 4;
  const int wm = w >> 1, wn = w & 1;
  const int row0 = blockIdx.y * 128, col0 = blockIdx.x * 128;
  const int kbeg = blockIdx.z * KC;
  const int kend = min(kbeg + KC, K);
  const int am = tid >> 1, akq = (tid & 1) << 4;
  const int bk = tid >> 3, bnq = (tid & 7) << 4;
  const int arow = row0 + am;

  f32x4 acc[4][4] = {};

  for (int k0 = kbeg; k0 < kend; k0 += 32) {
    float av[16], bv[16];
    if (arow < M) {
      const float* ap = A + (size_t)arow * lda + k0 + akq;
      if (k0 + akq + 15 < kend) {
#pragma unroll
        for (int u = 0; u < 4; ++u) {
          float4 t4 = *(const float4*)(ap + 4 * u);
          av[4*u] = t4.x; av[4*u+1] = t4.y; av[4*u+2] = t4.z; av[4*u+3] = t4.w;
        }
      } else {
#pragma unroll
        for (int e = 0; e < 16; ++e) av[e] = (k0 + akq + e < kend) ? ap[e] : 0.f;
      }
    } else {
#pragma unroll
      for (int e = 0; e < 16; ++e) av[e] = 0.f;
    }
    {
      const int kk = k0 + bk;
      if (kk < kend) {
        const float* bp = B + (size_t)kk * ldb + col0 + bnq;
        if (col0 + bnq + 15 < N) {
#pragma unroll
          for (int u = 0; u < 4; ++u) {
            float4 t4 = *(const float4*)(bp + 4 * u);
            bv[4*u] = t4.x; bv[4*u+1] = t4.y; bv[4*u+2] = t4.z; bv[4*u+3] = t4.w;
          }
        } else {
#pragma unroll
          for (int e = 0; e < 16; ++e)
            bv[e] = (col0 + bnq + e < N) ? bp[e] : 0.f;
        }
      } else {
#pragma unroll
        for (int e = 0; e < 16; ++e) bv[e] = 0.f;
      }
    }
    __syncthreads();
    {
      short8v p0, p1;
#pragma unroll
      for (int e = 0; e < 8; ++e) p0[e] = (short)f2bf(av[e]);
#pragma unroll
      for (int e = 0; e < 8; ++e) p1[e] = (short)f2bf(av[8 + e]);
      *(short8v*)&As[am][akq] = p0;
      *(short8v*)&As[am][akq + 8] = p1;
    }
#pragma unroll
    for (int u = 0; u < 4; ++u) {
      short4v pb;
#pragma unroll
      for (int e = 0; e < 4; ++e) pb[e] = (short)f2bf(bv[4 * u + e]);
      *(short4v*)&Bs[bk][bnq + 4 * u] = pb;
    }
    __syncthreads();
    short8v af[4];
#pragma unroll
    for (int mt = 0; mt < 4; ++mt)
      af[mt] = *(const short8v*)&As[wm * 64 + mt * 16 + l15][lhi * 8];
#pragma unroll
    for (int ct = 0; ct < 4; ++ct) {
      union { short8v v; unsigned short u[8]; } bf;
      const int nn = wn * 64 + ct * 16 + l15;
#pragma unroll
      for (int j = 0; j < 8; ++j) bf.u[j] = Bs[lhi * 8 + j][nn];
#pragma unroll
      for (int mt = 0; mt < 4; ++mt)
        acc[mt][ct] = __builtin_amdgcn_mfma_f32_16x16x32_bf16(
            af[mt], bf.v, acc[mt][ct], 0, 0, 0);
    }
  }

#pragma unroll
  for (int mt = 0; mt < 4; ++mt) {
    const int rb = row0 + wm * 64 + mt * 16 + lhi * 4;
#pragma unroll
    for (int u = 0; u < 4; ++u) {
      const int r = rb + u;
      if (r >= M) continue;
#pragma unroll
      for (int ct = 0; ct < 4; ++ct) {
        const int c = col0 + wn * 64 + ct * 16 + l15;
        if (c >= N) continue;
        float val = acc[mt][ct][u];
        if (ATOMIC) {
          atomicAdd(&C[(size_t)r * ldc + c], val);
        } else {
          if (bias) val += bias[c];
          C[(size_t)r * ldc + c] = val;
        }
      }
    }
  }
}

// ---------------------------------------------------------------------------
// C(MxN) += A^T @ B over K-chunk; A is (K x M) row-major, B is (K x N).
// Always atomic (split-K into pre-zeroed C). A staged transposed in LDS.
__global__ __launch_bounds__(256) void gemm_atb_mfma_k(
    const float* __restrict__ A, const float* __restrict__ B,
    float* __restrict__ C, int M, int N, int K,
    int lda, int ldb, int ldc, int KC) {
  __shared__ unsigned short As[128][40];
  __shared__ unsigned short Bs[32][132];
  const int tid = threadIdx.x;
  const int l = tid & 63, w = tid >> 6;
  const int l15 = l & 15, lhi = l >> 4;
  const int wm = w >> 1, wn = w & 1;
  const int row0 = blockIdx.y * 128, col0 = blockIdx.x * 128;
  const int kbeg = blockIdx.z * KC;
  const int kend = min(kbeg + KC, K);
  const int akk = tid >> 3, amq = (tid & 7) << 4;   // A: k-row, 16-m group
  const int bk = tid >> 3, bnq = (tid & 7) << 4;

  f32x4 acc[4][4] = {};

  for (int k0 = kbeg; k0 < kend; k0 += 32) {
    float av[16], bv[16];
    {
      const int kk = k0 + akk;
      if (kk < kend) {
        const float* ap = A + (size_t)kk * lda + row0 + amq;
        if (row0 + amq + 15 < M) {
#pragma unroll
          for (int u = 0; u < 4; ++u) {
            float4 t4 = *(const float4*)(ap + 4 * u);
            av[4*u] = t4.x; av[4*u+1] = t4.y; av[4*u+2] = t4.z; av[4*u+3] = t4.w;
          }
        } else {
#pragma unroll
          for (int e = 0; e < 16; ++e)
            av[e] = (row0 + amq + e < M) ? ap[e] : 0.f;
        }
      } else {
#pragma unroll
        for (int e = 0; e < 16; ++e) av[e] = 0.f;
      }
    }
    {
      const int kk = k0 + bk;
      if (kk < kend) {
        const float* bp = B + (size_t)kk * ldb + col0 + bnq;
        if (col0 + bnq + 15 < N) {
#pragma unroll
          for (int u = 0; u < 4; ++u) {
            float4 t4 = *(const float4*)(bp + 4 * u);
            bv[4*u] = t4.x; bv[4*u+1] = t4.y; bv[4*u+2] = t4.z; bv[4*u+3] = t4.w;
          }
        } else {
#pragma unroll
          for (int e = 0; e < 16; ++e)
            bv[e] = (col0 + bnq + e < N) ? bp[e] : 0.f;
        }
      } else {
#pragma unroll
        for (int e = 0; e < 16; ++e) bv[e] = 0.f;
      }
    }
    __syncthreads();
#pragma unroll
    for (int e = 0; e < 16; ++e) As[amq + e][akk] = f2bf(av[e]);   // transpose
#pragma unroll
    for (int u = 0; u < 4; ++u) {
      short4v pb;
#pragma unroll
      for (int e = 0; e < 4; ++e) pb[e] = (short)f2bf(bv[4 * u + e]);
      *(short4v*)&Bs[bk][bnq + 4 * u] = pb;
    }
    __syncthreads();
    short8v af[4];
#pragma unroll
    for (int mt = 0; mt < 4; ++mt)
      af[mt] = *(const short8v*)&As[wm * 64 + mt * 16 + l15][lhi * 8];
#pragma unroll
    for (int ct = 0; ct < 4; ++ct) {
      union { short8v v; unsigned short u[8]; } bf;
      const int nn = wn * 64 + ct * 16 + l15;
#pragma unroll
      for (int j = 0; j < 8; ++j) bf.u[j] = Bs[lhi * 8 + j][nn];
#pragma unroll
      for (int mt = 0; mt < 4; ++mt)
        acc[mt][ct] = __builtin_amdgcn_mfma_f32_16x16x32_bf16(
            af[mt], bf.v, acc[mt][ct], 0, 0, 0);
    }
  }

#pragma unroll
  for (int mt = 0; mt < 4; ++mt) {
    const int rb = row0 + wm * 64 + mt * 16 + lhi * 4;
#pragma unroll
    for (int u = 0; u < 4; ++u) {
      const int r = rb + u;
      if (r >= M) continue;
#pragma unroll
      for (int ct = 0; ct < 4; ++ct) {
        const int c = col0 + wn * 64 + ct * 16 + l15;
        if (c >= N) continue;
        atomicAdd(&C[(size_t)r * ldc + c], acc[mt][ct][u]);
      }
    }
  }
}

// ---------------------------------------------------------------------------
// rel0 via MFMA: relbf[i,d,f] = bf16(rel_w[i,d,f] + sum_j tanh(q[i,d]k[j,d]) v[j,f])
// Block: (d-block of 128) x (i). K = j (100 padded to 128). f looped 4x128.
__global__ __launch_bounds__(256) void rel0_mfma_k(
    const float* __restrict__ qm, const float* __restrict__ km,
    const float* __restrict__ vm, const float* __restrict__ rel_w,
    unsigned short* __restrict__ relbf) {
  __shared__ unsigned short Ts[128][136];   // [d][j]
  __shared__ unsigned short Vs[128][136];   // [j][f]
  __shared__ float qv[128];
  const int i = blockIdx.y;
  const int d0 = blockIdx.x * 128;
  const int tid = threadIdx.x;
  const int l = tid & 63, w = tid >> 6;
  const int l15 = l & 15, lhi = l >> 4;
  const int wm = w >> 1, wn = w & 1;

  if (tid < 128) qv[tid] = qm[(size_t)i * DDIM + d0 + tid];
  __syncthreads();
  // Ts[d][j] = tanh(qv[d] * km[j][d0+d]) for j<100, else 0
#pragma unroll
  for (int p = 0; p < 8; ++p) {
    int g = p * 2048 + tid * 8;
    int j = g >> 7, dd = g & 127;
    if (j < MMEM) {
      const float* kp = km + (size_t)j * DDIM + d0 + dd;
      float4 k0v = *(const float4*)kp;
      float4 k1v = *(const float4*)(kp + 4);
      float kv[8] = {k0v.x, k0v.y, k0v.z, k0v.w, k1v.x, k1v.y, k1v.z, k1v.w};
#pragma unroll
      for (int e = 0; e < 8; ++e)
        Ts[dd + e][j] = f2bf(tanhf(qv[dd + e] * kv[e]));
    } else {
#pragma unroll
      for (int e = 0; e < 8; ++e) Ts[dd + e][j] = 0;
    }
  }

  for (int f0 = 0; f0 < DDIM; f0 += 128) {
    __syncthreads();   // Ts ready (first iter) / prior MFMA reads done
#pragma unroll
    for (int p = 0; p < 8; ++p) {
      int g = p * 2048 + tid * 8;
      int j = g >> 7, ff = g & 127;
      short8v pv;
      if (j < MMEM) {
        const float* vp = vm + (size_t)j * DDIM + f0 + ff;
        float4 v0 = *(const float4*)vp;
        float4 v1 = *(const float4*)(vp + 4);
        pv[0] = (short)f2bf(v0.x); pv[1] = (short)f2bf(v0.y);
        pv[2] = (short)f2bf(v0.z); pv[3] = (short)f2bf(v0.w);
        pv[4] = (short)f2bf(v1.x); pv[5] = (short)f2bf(v1.y);
        pv[6] = (short)f2bf(v1.z); pv[7] = (short)f2bf(v1.w);
      } else {
#pragma unroll
        for (int e = 0; e < 8; ++e) pv[e] = 0;
      }
      *(short8v*)&Vs[j][ff] = pv;
    }
    __syncthreads();
    f32x4 acc[4][4] = {};
#pragma unroll
    for (int ks = 0; ks < 4; ++ks) {
      const int kb = ks * 32;
      short8v af[4];
#pragma unroll
      for (int mt = 0; mt < 4; ++mt)
        af[mt] = *(const short8v*)&Ts[wm * 64 + mt * 16 + l15][kb + lhi * 8];
#pragma unroll
      for (int ct = 0; ct < 4; ++ct) {
        union { short8v v; unsigned short u[8]; } bf;
        const int nn = wn * 64 + ct * 16 + l15;
#pragma unroll
        for (int jj = 0; jj < 8; ++jj) bf.u[jj] = Vs[kb + lhi * 8 + jj][nn];
#pragma unroll
        for (int mt = 0; mt < 4; ++mt)
          acc[mt][ct] = __builtin_amdgcn_mfma_f32_16x16x32_bf16(
              af[mt], bf.v, acc[mt][ct], 0, 0, 0);
      }
    }
    // epilogue: add rel_w, store bf16
#pragma unroll
    for (int mt = 0; mt < 4; ++mt) {
#pragma unroll
      for (int u = 0; u < 4; ++u) {
        const int d = d0 + wm * 64 + mt * 16 + lhi * 4 + u;
        const size_t base = (size_t)i * 262144 + (size_t)d * DDIM;
#pragma unroll
        for (int ct = 0; ct < 4; ++ct) {
          const int f = f0 + wn * 64 + ct * 16 + l15;
          float val = rel_w[base + f] + acc[mt][ct][u];
          relbf[base + f] = f2bf(val);
        }
      }
    }
  }
}

// ---------------------------------------------------------------------------
// memgemm: partial[z] = relbf(100x262144 bf16) chunk_z @ Wr1(262144x512 f32)
#define MGK 262144
#define MGKC 1024
#define MGCHUNK 256
__global__ __launch_bounds__(512) void memgemm_k(
    const unsigned short* __restrict__ Ag, const float* __restrict__ Bg,
    float* __restrict__ partial) {
  __shared__ unsigned short As[128][40];
  __shared__ unsigned short Bs[32][520];
  const int tid = threadIdx.x;
  const int l = tid & 63;
  const int w = tid >> 6;
  const int n0 = w * 64;
  const int kbeg = blockIdx.x * MGKC;
  const int arow = tid >> 2, akq = tid & 3;
  const int bkrow = tid >> 4, bnq = tid & 15;
  const int l15 = l & 15, lhi = l >> 4;

  f32x4 acc[8][4] = {};

  for (int t = 0; t < MGKC / 32; ++t) {
    const int kb = kbeg + t * 32;
    short8v av;
    if (arow < MMEM) {
      av = *(const short8v*)(Ag + (size_t)arow * MGK + kb + akq * 8);
    } else {
#pragma unroll
      for (int e = 0; e < 8; ++e) av[e] = 0;
    }
    float4 bv[8];
    const float* bp = Bg + (size_t)(kb + bkrow) * DDIM + bnq * 32;
#pragma unroll
    for (int u = 0; u < 8; ++u) bv[u] = *(const float4*)(bp + u * 4);

    __syncthreads();
    *(short8v*)&As[arow][akq * 8] = av;
#pragma unroll
    for (int u = 0; u < 4; ++u) {
      short8v pb;
      pb[0] = (short)f2bf(bv[2*u].x);   pb[1] = (short)f2bf(bv[2*u].y);
      pb[2] = (short)f2bf(bv[2*u].z);   pb[3] = (short)f2bf(bv[2*u].w);
      pb[4] = (short)f2bf(bv[2*u+1].x); pb[5] = (short)f2bf(bv[2*u+1].y);
      pb[6] = (short)f2bf(bv[2*u+1].z); pb[7] = (short)f2bf(bv[2*u+1].w);
      *(short8v*)&Bs[bkrow][bnq * 32 + u * 8] = pb;
    }
    __syncthreads();
    short8v afr[8];
#pragma unroll
    for (int mt = 0; mt < 8; ++mt)
      afr[mt] = *(const short8v*)&As[mt * 16 + l15][lhi * 8];
#pragma unroll
    for (int ct = 0; ct < 4; ++ct) {
      union { short8v v; unsigned short u[8]; } bf;
      const int nn = n0 + ct * 16 + l15;
#pragma unroll
      for (int j = 0; j < 8; ++j) bf.u[j] = Bs[lhi * 8 + j][nn];
#pragma unroll
      for (int mt = 0; mt < 8; ++mt)
        acc[mt][ct] = __builtin_amdgcn_mfma_f32_16x16x32_bf16(
            afr[mt], bf.v, acc[mt][ct], 0, 0, 0);
    }
  }

  float* pw = partial + (size_t)blockIdx.x * (MMEM * DDIM);
#pragma unroll
  for (int mt = 0; mt < 8; ++mt) {
    const int r0 = mt * 16 + lhi * 4;
#pragma unroll
    for (int r = 0; r < 4; ++r) {
      const int row = r0 + r;
      if (row < MMEM) {
#pragma unroll
        for (int ct = 0; ct < 4; ++ct)
          pw[(size_t)row * DDIM + n0 + ct * 16 + l15] = acc[mt][ct][r];
      }
    }
  }
}

__global__ __launch_bounds__(256) void reduce_partials_k(
    const float* __restrict__ p, float* __restrict__ out) {
  int i = blockIdx.x * 256 + threadIdx.x;
  int z0 = blockIdx.y * 64;
  float s = 0.f;
  for (int z = 0; z < 64; ++z) s += p[(size_t)(z0 + z) * (MMEM * DDIM) + i];
  atomicAdd(&out[i], s);
}

// ---------------------------------------------------------------------------
__global__ __launch_bounds__(256) void softmax100_k(float* __restrict__ x,
                                                    int nrows, int ld) {
  int wid = threadIdx.x >> 6;
  int lane = threadIdx.x & 63;
  int row = blockIdx.x * 4 + wid;
  if (row >= nrows) return;
  float* xr = x + (size_t)row * ld;
  float v0 = xr[lane];
  bool has1 = (lane + 64) < MMEM;
  float v1 = has1 ? xr[lane + 64] : -3.4e38f;
  float m = fmaxf(v0, v1);
#pragma unroll
  for (int o = 32; o; o >>= 1) m = fmaxf(m, __shfl_xor(m, o, 64));
  float e0 = expf(v0 - m);
  float e1 = has1 ? expf(v1 - m) : 0.f;
  float s = e0 + e1;
#pragma unroll
  for (int o = 32; o; o >>= 1) s += __shfl_xor(s, o, 64);
  float inv = 1.f / s;
  xr[lane] = e0 * inv;
  if (has1) xr[lane + 64] = e1 * inv;
}

__global__ __launch_bounds__(512) void colsum_k(const float* __restrict__ A,
                                                float* __restrict__ out) {
  int d = threadIdx.x;
  int r0 = blockIdx.x * 512;
  float a = 0.f;
  for (int r = 0; r < 512; ++r) a += A[(size_t)(r0 + r) * DDIM + d];
  atomicAdd(&out[d], a);
}

__global__ __launch_bounds__(256) void ip4sum_k(const float* __restrict__ S,
                                                const float* __restrict__ rel_w,
                                                float* __restrict__ out) {
  __shared__ float sv[128];
  int r0 = blockIdx.x * 128;
  int tid = threadIdx.x;
  if (tid < 128) sv[tid] = S[r0 + tid];
  __syncthreads();
  float a0 = 0.f, a1 = 0.f;
  for (int r = 0; r < 128; ++r) {
    const float* row = rel_w + (size_t)(r0 + r) * DDIM;
    float s = sv[r];
    a0 = fmaf(s, row[tid], a0);
    a1 = fmaf(s, row[tid + 256], a1);
  }
  atomicAdd(&out[tid], a0);
  atomicAdd(&out[tid + 256], a1);
}

__global__ __launch_bounds__(256) void assemble_item_k(
    float* __restrict__ item, const float* __restrict__ item_w,
    const float* __restrict__ s4, const float* __restrict__ s2) {
  int idx = blockIdx.x * 256 + threadIdx.x;
  int d = idx >> 9, f = idx & 511;
  item[idx] += item_w[idx] + s4[d] * s2[f];
}

__global__ __launch_bounds__(256) void ln300_k(const float* __restrict__ x,
                                               const float* __restrict__ g,
                                               const float* __restrict__ bb,
                                               float* __restrict__ y) {
  __shared__ float r1[4], r2[4];
  int row = blockIdx.x, tid = threadIdx.x;
  const float* xr = x + (size_t)row * QKVW;
  float v1 = xr[tid];
  float v2 = (tid + 256 < QKVW) ? xr[tid + 256] : 0.f;
  float s = v1 + v2, q = v1 * v1 + v2 * v2;
#pragma unroll
  for (int o = 32; o; o >>= 1) { s += __shfl_xor(s, o, 64); q += __shfl_xor(q, o, 64); }
  if ((tid & 63) == 0) { r1[tid >> 6] = s; r2[tid >> 6] = q; }
  __syncthreads();
  s = r1[0] + r1[1] + r1[2] + r1[3];
  q = r2[0] + r2[1] + r2[2] + r2[3];
  float mean = s * (1.f / 300.f);
  float var = q * (1.f / 300.f) - mean * mean;
  float inv = rsqrtf(var + 512.0f);
  float* yr = y + (size_t)row * QKVW;
  yr[tid] = (v1 - mean) * inv * g[tid] + bb[tid];
  if (tid + 256 < QKVW)
    yr[tid + 256] = (v2 - mean) * inv * g[tid + 256] + bb[tid + 256];
}

__global__ __launch_bounds__(256) void split_qkv_k(const float* __restrict__ y,
                                                   float* __restrict__ qm,
                                                   float* __restrict__ km,
                                                   float* __restrict__ vm) {
  int idx = blockIdx.x * 256 + threadIdx.x;
  int d = idx / MMEM, i = idx % MMEM;
  const float* row = y + (size_t)d * QKVW;
  qm[(size_t)i * DDIM + d] = row[i];
  km[(size_t)i * DDIM + d] = row[MMEM + i];
  vm[(size_t)i * DDIM + d] = row[2 * MMEM + i];
}

__global__ __launch_bounds__(256) void mn_k(const float* __restrict__ macc,
                                            const float* __restrict__ br1,
                                            float* __restrict__ mn,
                                            float* __restrict__ mnT) {
  __shared__ float r1[4];
  int i = blockIdx.x, tid = threadIdx.x;
  float v0 = macc[(size_t)i * DDIM + tid] + br1[tid];
  float v1 = macc[(size_t)i * DDIM + tid + 256] + br1[tid + 256];
  float q = v0 * v0 + v1 * v1;
#pragma unroll
  for (int o = 32; o; o >>= 1) q += __shfl_xor(q, o, 64);
  if ((tid & 63) == 0) r1[tid >> 6] = q;
  __syncthreads();
  q = r1[0] + r1[1] + r1[2] + r1[3];
  float inv = 1.f / fmaxf(sqrtf(q), 1e-12f);
  float a = v0 * inv, b = v1 * inv;
  mn[(size_t)i * DDIM + tid] = a;
  mn[(size_t)i * DDIM + tid + 256] = b;
  mnT[(size_t)tid * MMEM + i] = a;
  mnT[(size_t)(tid + 256) * MMEM + i] = b;
}

__global__ void write_mf_k(const float* __restrict__ mf, float* __restrict__ out) {
  __shared__ float tile[32][33];
  int b = blockIdx.z, hw0 = blockIdx.x * 32, c0 = blockIdx.y * 32;
  int tx = threadIdx.x, ty = threadIdx.y;
#pragma unroll
  for (int i = 0; i < 32; i += 8)
    tile[ty + i][tx] = mf[((size_t)b * HWSZ + hw0 + ty + i) * DDIM + c0 + tx];
  __syncthreads();
#pragma unroll
  for (int i = 0; i < 32; i += 8)
    out[(size_t)b * 4194304 + (size_t)(512 + c0 + ty + i) * HWSZ + hw0 + tx] =
        tile[tx][ty + i];
}

// ---------------------------------------------------------------------------
extern "C" void kernel_launch(void* const* d_in, const int* in_sizes, int n_in,
                              void* d_out, int out_size, void* d_ws, size_t ws_size,
                              hipStream_t stream) {
  (void)in_sizes; (void)n_in; (void)out_size; (void)ws_size;
  const float* fea    = (const float*)d_in[0];
  const float* item_w = (const float*)d_in[1];
  const float* rel_w  = (const float*)d_in[2];
  const float* W1     = (const float*)d_in[3];
  const float* b1     = (const float*)d_in[4];
  const float* W2     = (const float*)d_in[5];
  const float* b2     = (const float*)d_in[6];
  const float* W3     = (const float*)d_in[7];
  const float* b3     = (const float*)d_in[8];
  const float* Wqkv   = (const float*)d_in[9];
  const float* bqkv   = (const float*)d_in[10];
  const float* ln_g   = (const float*)d_in[11];
  const float* ln_b   = (const float*)d_in[12];
  const float* Wr1    = (const float*)d_in[13];
  const float* br1    = (const float*)d_in[14];
  float* out = (float*)d_out;
  float* ws = (float*)d_ws;

  // Workspace layout (floats), ~258 MB total.
  float* qn      = ws;                      // 8,388,608
  float* ip1     = qn      + 8388608;       // 8,388,608
  float* ip2     = ip1     + 8388608;       // 8,388,608
  float* ip3     = ip2     + 8388608;       // 1,638,400 (ld=100)
  float* addr    = ip3     + 1638400;       // 2,097,152 (ld=128)
  float* mf      = addr    + 2097152;       // 8,388,608
  float* partial = mf      + 8388608;       // 13,107,200
  unsigned short* relbf = (unsigned short*)(partial + 13107200);  // 26,214,400 u16
  float* S       = partial + 13107200 + 13107200;  // 51,200  (zeroed)
  float* ip4sum  = S       + 51200;         // 512     (zeroed)
  float* ip2sum  = ip4sum  + 512;           // 512     (zeroed)
  float* item    = ip2sum  + 512;           // 262,144 (zeroed)
  float* memacc  = item    + 262144;        // 51,200  (zeroed)
  float* qkv     = memacc  + 51200;         // 153,600
  float* qkvln   = qkv     + 153600;        // 153,600
  float* qm      = qkvln   + 153600;        // 51,200
  float* km      = qm      + 51200;         // 51,200
  float* vm      = km      + 51200;         // 51,200
  float* mnb     = vm      + 51200;         // 51,200
  float* mnT     = mnb     + 51200;         // 51,200
  float* invn    = mnT     + 51200;         // 16,384

  hipMemsetAsync(S, 0, (size_t)(51200 + 512 + 512 + 262144 + 51200) * sizeof(float),
                 stream);

  // 1) qn = l2norm(tokens of fea); fused fea->out copy
  rownorm_k<<<64, 256, 0, stream>>>(fea, invn);
  make_qn_k<<<dim3(128, 16, 4), dim3(32, 8), 0, stream>>>(fea, invn, qn, out);

  // 2) ip1/ip2/ip3 + softmax
  gemm_mfma_k<false><<<dim3(4, 128), 256, 0, stream>>>(
      qn, W1, b1, ip1, NTOK, DDIM, DDIM, DDIM, DDIM, DDIM, DDIM);
  gemm_mfma_k<false><<<dim3(4, 128), 256, 0, stream>>>(
      qn, W2, b2, ip2, NTOK, DDIM, DDIM, DDIM, DDIM, DDIM, DDIM);
  gemm_mfma_k<false><<<dim3(1, 128), 256, 0, stream>>>(
      qn, W3, b3, ip3, NTOK, MMEM, DDIM, DDIM, MMEM, MMEM, DDIM);
  softmax100_k<<<4096, 256, 0, stream>>>(ip3, NTOK, MMEM);

  // 3) item1 = ip1^T@ip1, S = ip3^T@ip2 (transpose-free split-K), colsum, ip4sum
  gemm_atb_mfma_k<<<dim3(4, 4, 16), 256, 0, stream>>>(
      ip1, ip1, item, DDIM, DDIM, NTOK, DDIM, DDIM, DDIM, 1024);
  gemm_atb_mfma_k<<<dim3(4, 1, 16), 256, 0, stream>>>(
      ip3, ip2, S, MMEM, DDIM, NTOK, MMEM, DDIM, DDIM, 1024);
  colsum_k<<<32, 512, 0, stream>>>(ip2, ip2sum);
  ip4sum_k<<<400, 256, 0, stream>>>(S, rel_w, ip4sum);

  // 4) item += item_w + outer(ip4sum, ip2sum)
  assemble_item_k<<<1024, 256, 0, stream>>>(item, item_w, ip4sum, ip2sum);

  // 5) qkv = item@Wqkv + bqkv; LN(eps=512); split
  gemm_mfma_k<false><<<dim3(3, 4), 256, 0, stream>>>(
      item, Wqkv, bqkv, qkv, DDIM, QKVW, DDIM, DDIM, QKVW, QKVW, DDIM);
  ln300_k<<<512, 256, 0, stream>>>(qkv, ln_g, ln_b, qkvln);
  split_qkv_k<<<200, 256, 0, stream>>>(qkvln, qm, km, vm);

  // 6) relbf = bf16(rel_w + einsum(tanh(q*k), v))  -- MFMA
  rel0_mfma_k<<<dim3(4, MMEM), 256, 0, stream>>>(qm, km, vm, rel_w, relbf);

  // 7) memory = relbf @ Wr1 (bf16 MFMA, split-K partials)
  memgemm_k<<<dim3(MGCHUNK), 512, 0, stream>>>(relbf, Wr1, partial);
  reduce_partials_k<<<dim3(200, 4), 256, 0, stream>>>(partial, memacc);
  mn_k<<<MMEM, 256, 0, stream>>>(memacc, br1, mnb, mnT);

  // 8) addr = softmax(qn@mnT); mf = addr@mnb
  gemm_mfma_k<false><<<dim3(1, 128), 256, 0, stream>>>(
      qn, mnT, nullptr, addr, NTOK, MMEM, DDIM, DDIM, MMEM, 128, DDIM);
  softmax100_k<<<4096, 256, 0, stream>>>(addr, NTOK, 128);
  gemm_mfma_k<false><<<dim3(4, 128), 256, 0, stream>>>(
      addr, mnb, nullptr, mf, NTOK, DDIM, MMEM, 128, DDIM, DDIM, MMEM);

  // 9) out second half: mf^T
  write_mf_k<<<dim3(128, 16, 4), dim3(32, 8), 0, stream>>>(mf, out);
}

// Round 5
// 577.603 us; speedup vs baseline: 4.0617x; 1.1841x over previous
//
#include <hip/hip_runtime.h>
#include <hip/hip_bf16.h>

#define NTOK 16384
#define DDIM 512
#define MMEM 100
#define HWSZ 4096
#define QKVW 300

typedef __attribute__((ext_vector_type(8))) short short8v;   // 8 bf16
typedef __attribute__((ext_vector_type(4))) short short4v;   // 4 bf16
typedef __attribute__((ext_vector_type(4))) float f32x4;

__device__ __forceinline__ unsigned short f2bf(float x) {
  union { __hip_bfloat16 h; unsigned short u; } cv;
  cv.h = __float2bfloat16(x);
  return cv.u;
}
__device__ __forceinline__ float bf2f(unsigned short u) {
  union { unsigned int u; float f; } v; v.u = ((unsigned int)u) << 16;
  return v.f;
}

// ---------------------------------------------------------------------------
// Convert the four weight matrices to bf16 (3.3 MB total, once per call).
__global__ __launch_bounds__(256) void cvtw_k(
    const float* __restrict__ W1, const float* __restrict__ W2,
    const float* __restrict__ W3, const float* __restrict__ Wq,
    unsigned short* __restrict__ o1, unsigned short* __restrict__ o2,
    unsigned short* __restrict__ o3, unsigned short* __restrict__ oq) {
  int idx = blockIdx.x * 256 + threadIdx.x;
  const float* s; unsigned short* d; int off;
  if (idx < 262144)      { s = W1; d = o1; off = idx; }
  else if (idx < 524288) { s = W2; d = o2; off = idx - 262144; }
  else if (idx < 575488) { s = W3; d = o3; off = idx - 524288; }
  else if (idx < 729088) { s = Wq; d = oq; off = idx - 575488; }
  else return;
  d[off] = f2bf(s[off]);
}

// ---------------------------------------------------------------------------
// feat_k: per 32-hw block, read fea[b, :, hw0:hw0+32] once; emit
//  (a) out[b, 0:512, hw] copy  (b) qnbf[n, :] = l2norm(token) in bf16.
__global__ __launch_bounds__(256) void feat_k(const float* __restrict__ fea,
                                              unsigned short* __restrict__ qnbf,
                                              float* __restrict__ out) {
  __shared__ float tile[512][33];
  __shared__ float psum[8][32];
  __shared__ float invn_s[32];
  const int bid = blockIdx.x;                 // 512
  const int b = bid >> 7, hw0 = (bid & 127) * 32;
  const int t = threadIdx.x;
  const int hwo = t & 31, cg = t >> 5;        // load phase roles
  const float* src = fea + (size_t)b * DDIM * HWSZ + hw0;
  float* dst = out + (size_t)b * (2 * DDIM) * HWSZ + hw0;
  float ss = 0.f;
#pragma unroll 8
  for (int i = 0; i < 64; ++i) {
    int c = cg * 64 + i;
    float v = src[(size_t)c * HWSZ + hwo];
    tile[c][hwo] = v;
    dst[(size_t)c * HWSZ + hwo] = v;
    ss += v * v;
  }
  psum[cg][hwo] = ss;
  __syncthreads();
  if (t < 32) {
    float s = 0.f;
#pragma unroll
    for (int j = 0; j < 8; ++j) s += psum[j][t];
    invn_s[t] = 1.f / fmaxf(sqrtf(s), 1e-12f);
  }
  __syncthreads();
  const int tok = t & 31, c0 = (t >> 5) * 64;  // write phase roles
  const float inv = invn_s[tok];
  unsigned short* qp = qnbf + ((size_t)(b * HWSZ + hw0 + tok)) * DDIM + c0;
#pragma unroll
  for (int e8 = 0; e8 < 8; ++e8) {
    short8v p;
#pragma unroll
    for (int e = 0; e < 8; ++e)
      p[e] = (short)f2bf(tile[c0 + e8 * 8 + e][tok] * inv);
    *(short8v*)(qp + e8 * 8) = p;
  }
}

// ---------------------------------------------------------------------------
// Pure-bf16 MFMA GEMM: C(MxN) = A@B [+bias]; A,B bf16; C f32 or bf16.
// 128x128 tile, BK=32, 256 threads (4 waves 2x2, each 64x64).
template<bool OUTBF>
__global__ __launch_bounds__(256) void gemm_bf16_k(
    const unsigned short* __restrict__ A, const unsigned short* __restrict__ B,
    const float* __restrict__ bias, void* __restrict__ Cv,
    int M, int N, int K, int lda, int ldb, int ldc) {
  __shared__ unsigned short As[128][40];
  __shared__ unsigned short Bs[32][132];
  const int tid = threadIdx.x;
  const int l = tid & 63, w = tid >> 6;
  const int l15 = l & 15, lhi = l >> 4;
  const int wm = w >> 1, wn = w & 1;
  const int row0 = blockIdx.y * 128, col0 = blockIdx.x * 128;
  const int am = tid >> 1, akq = (tid & 1) << 4;
  const int bk = tid >> 3, bnq = (tid & 7) << 4;
  const int arow = row0 + am;
  f32x4 acc[4][4] = {};

  for (int k0 = 0; k0 < K; k0 += 32) {
    short8v av0 = {}, av1 = {}, bv0 = {}, bv1 = {};
    if (arow < M && k0 + akq < K) {
      const unsigned short* ap = A + (size_t)arow * lda + k0 + akq;
      if (k0 + akq + 15 < K) {
        av0 = *(const short8v*)ap;
        av1 = *(const short8v*)(ap + 8);
      } else {
#pragma unroll
        for (int e = 0; e < 8; ++e) {
          av0[e] = (k0 + akq + e < K) ? (short)ap[e] : (short)0;
          av1[e] = (k0 + akq + 8 + e < K) ? (short)ap[8 + e] : (short)0;
        }
      }
    }
    {
      const int kk = k0 + bk;
      if (kk < K) {
        const unsigned short* bp = B + (size_t)kk * ldb + col0 + bnq;
        if (col0 + bnq + 15 < N) {
          bv0 = *(const short8v*)bp;
          bv1 = *(const short8v*)(bp + 8);
        } else {
#pragma unroll
          for (int e = 0; e < 8; ++e) {
            bv0[e] = (col0 + bnq + e < N) ? (short)bp[e] : (short)0;
            bv1[e] = (col0 + bnq + 8 + e < N) ? (short)bp[8 + e] : (short)0;
          }
        }
      }
    }
    __syncthreads();
    *(short8v*)&As[am][akq] = av0;
    *(short8v*)&As[am][akq + 8] = av1;
    *(short8v*)&Bs[bk][bnq] = bv0;
    *(short8v*)&Bs[bk][bnq + 8] = bv1;
    __syncthreads();
    short8v af[4];
#pragma unroll
    for (int mt = 0; mt < 4; ++mt)
      af[mt] = *(const short8v*)&As[wm * 64 + mt * 16 + l15][lhi * 8];
#pragma unroll
    for (int ct = 0; ct < 4; ++ct) {
      union { short8v v; unsigned short u[8]; } bf;
      const int nn = wn * 64 + ct * 16 + l15;
#pragma unroll
      for (int j = 0; j < 8; ++j) bf.u[j] = Bs[lhi * 8 + j][nn];
#pragma unroll
      for (int mt = 0; mt < 4; ++mt)
        acc[mt][ct] = __builtin_amdgcn_mfma_f32_16x16x32_bf16(
            af[mt], bf.v, acc[mt][ct], 0, 0, 0);
    }
  }

#pragma unroll
  for (int mt = 0; mt < 4; ++mt) {
    const int rb = row0 + wm * 64 + mt * 16 + lhi * 4;
#pragma unroll
    for (int u = 0; u < 4; ++u) {
      const int r = rb + u;
      if (r >= M) continue;
#pragma unroll
      for (int ct = 0; ct < 4; ++ct) {
        const int c = col0 + wn * 64 + ct * 16 + l15;
        if (c >= N) continue;
        float val = acc[mt][ct][u];
        if (bias) val += bias[c];
        if (OUTBF) ((unsigned short*)Cv)[(size_t)r * ldc + c] = f2bf(val);
        else       ((float*)Cv)[(size_t)r * ldc + c] = val;
      }
    }
  }
}

// ---------------------------------------------------------------------------
// C(MxN) += A^T @ B over a K-chunk; A (KxM) bf16, B (KxN) bf16, atomic f32 C.
__global__ __launch_bounds__(256) void atb_bf16_k(
    const unsigned short* __restrict__ A, const unsigned short* __restrict__ B,
    float* __restrict__ C, int M, int N, int K,
    int lda, int ldb, int ldc, int KC) {
  __shared__ unsigned short As[128][40];
  __shared__ unsigned short Bs[32][132];
  const int tid = threadIdx.x;
  const int l = tid & 63, w = tid >> 6;
  const int l15 = l & 15, lhi = l >> 4;
  const int wm = w >> 1, wn = w & 1;
  const int row0 = blockIdx.y * 128, col0 = blockIdx.x * 128;
  const int kbeg = blockIdx.z * KC;
  const int kend = min(kbeg + KC, K);
  const int akk = tid >> 3, amq = (tid & 7) << 4;
  const int bk = tid >> 3, bnq = (tid & 7) << 4;
  f32x4 acc[4][4] = {};

  for (int k0 = kbeg; k0 < kend; k0 += 32) {
    unsigned short av[16]; short8v bv0 = {}, bv1 = {};
    {
      const int kk = k0 + akk;
      if (kk < kend) {
        const unsigned short* ap = A + (size_t)kk * lda + row0 + amq;
        if (row0 + amq + 15 < M) {
          *(short8v*)&av[0] = *(const short8v*)ap;
          *(short8v*)&av[8] = *(const short8v*)(ap + 8);
        } else {
#pragma unroll
          for (int e = 0; e < 16; ++e)
            av[e] = (row0 + amq + e < M) ? ap[e] : 0;
        }
      } else {
#pragma unroll
        for (int e = 0; e < 16; ++e) av[e] = 0;
      }
    }
    {
      const int kk = k0 + bk;
      if (kk < kend) {
        const unsigned short* bp = B + (size_t)kk * ldb + col0 + bnq;
        if (col0 + bnq + 15 < N) {
          bv0 = *(const short8v*)bp;
          bv1 = *(const short8v*)(bp + 8);
        } else {
#pragma unroll
          for (int e = 0; e < 8; ++e) {
            bv0[e] = (col0 + bnq + e < N) ? (short)bp[e] : (short)0;
            bv1[e] = (col0 + bnq + 8 + e < N) ? (short)bp[8 + e] : (short)0;
          }
        }
      }
    }
    __syncthreads();
#pragma unroll
    for (int e = 0; e < 16; ++e) As[amq + e][akk] = av[e];   // transposed
    *(short8v*)&Bs[bk][bnq] = bv0;
    *(short8v*)&Bs[bk][bnq + 8] = bv1;
    __syncthreads();
    short8v af[4];
#pragma unroll
    for (int mt = 0; mt < 4; ++mt)
      af[mt] = *(const short8v*)&As[wm * 64 + mt * 16 + l15][lhi * 8];
#pragma unroll
    for (int ct = 0; ct < 4; ++ct) {
      union { short8v v; unsigned short u[8]; } bf;
      const int nn = wn * 64 + ct * 16 + l15;
#pragma unroll
      for (int j = 0; j < 8; ++j) bf.u[j] = Bs[lhi * 8 + j][nn];
#pragma unroll
      for (int mt = 0; mt < 4; ++mt)
        acc[mt][ct] = __builtin_amdgcn_mfma_f32_16x16x32_bf16(
            af[mt], bf.v, acc[mt][ct], 0, 0, 0);
    }
  }

#pragma unroll
  for (int mt = 0; mt < 4; ++mt) {
    const int rb = row0 + wm * 64 + mt * 16 + lhi * 4;
#pragma unroll
    for (int u = 0; u < 4; ++u) {
      const int r = rb + u;
      if (r >= M) continue;
#pragma unroll
      for (int ct = 0; ct < 4; ++ct) {
        const int c = col0 + wn * 64 + ct * 16 + l15;
        if (c >= N) continue;
        atomicAdd(&C[(size_t)r * ldc + c], acc[mt][ct][u]);
      }
    }
  }
}

// ---------------------------------------------------------------------------
// rel0 via MFMA (unchanged from R4, known-good)
__global__ __launch_bounds__(256) void rel0_mfma_k(
    const float* __restrict__ qm, const float* __restrict__ km,
    const float* __restrict__ vm, const float* __restrict__ rel_w,
    unsigned short* __restrict__ relbf) {
  __shared__ unsigned short Ts[128][136];
  __shared__ unsigned short Vs[128][136];
  __shared__ float qv[128];
  const int i = blockIdx.y;
  const int d0 = blockIdx.x * 128;
  const int tid = threadIdx.x;
  const int l = tid & 63, w = tid >> 6;
  const int l15 = l & 15, lhi = l >> 4;
  const int wm = w >> 1, wn = w & 1;

  if (tid < 128) qv[tid] = qm[(size_t)i * DDIM + d0 + tid];
  __syncthreads();
#pragma unroll
  for (int p = 0; p < 8; ++p) {
    int g = p * 2048 + tid * 8;
    int j = g >> 7, dd = g & 127;
    if (j < MMEM) {
      const float* kp = km + (size_t)j * DDIM + d0 + dd;
      float4 k0v = *(const float4*)kp;
      float4 k1v = *(const float4*)(kp + 4);
      float kv[8] = {k0v.x, k0v.y, k0v.z, k0v.w, k1v.x, k1v.y, k1v.z, k1v.w};
#pragma unroll
      for (int e = 0; e < 8; ++e)
        Ts[dd + e][j] = f2bf(tanhf(qv[dd + e] * kv[e]));
    } else {
#pragma unroll
      for (int e = 0; e < 8; ++e) Ts[dd + e][j] = 0;
    }
  }

  for (int f0 = 0; f0 < DDIM; f0 += 128) {
    __syncthreads();
#pragma unroll
    for (int p = 0; p < 8; ++p) {
      int g = p * 2048 + tid * 8;
      int j = g >> 7, ff = g & 127;
      short8v pv;
      if (j < MMEM) {
        const float* vp = vm + (size_t)j * DDIM + f0 + ff;
        float4 v0 = *(const float4*)vp;
        float4 v1 = *(const float4*)(vp + 4);
        pv[0] = (short)f2bf(v0.x); pv[1] = (short)f2bf(v0.y);
        pv[2] = (short)f2bf(v0.z); pv[3] = (short)f2bf(v0.w);
        pv[4] = (short)f2bf(v1.x); pv[5] = (short)f2bf(v1.y);
        pv[6] = (short)f2bf(v1.z); pv[7] = (short)f2bf(v1.w);
      } else {
#pragma unroll
        for (int e = 0; e < 8; ++e) pv[e] = 0;
      }
      *(short8v*)&Vs[j][ff] = pv;
    }
    __syncthreads();
    f32x4 acc[4][4] = {};
#pragma unroll
    for (int ks = 0; ks < 4; ++ks) {
      const int kb = ks * 32;
      short8v af[4];
#pragma unroll
      for (int mt = 0; mt < 4; ++mt)
        af[mt] = *(const short8v*)&Ts[wm * 64 + mt * 16 + l15][kb + lhi * 8];
#pragma unroll
      for (int ct = 0; ct < 4; ++ct) {
        union { short8v v; unsigned short u[8]; } bf;
        const int nn = wn * 64 + ct * 16 + l15;
#pragma unroll
        for (int jj = 0; jj < 8; ++jj) bf.u[jj] = Vs[kb + lhi * 8 + jj][nn];
#pragma unroll
        for (int mt = 0; mt < 4; ++mt)
          acc[mt][ct] = __builtin_amdgcn_mfma_f32_16x16x32_bf16(
              af[mt], bf.v, acc[mt][ct], 0, 0, 0);
      }
    }
#pragma unroll
    for (int mt = 0; mt < 4; ++mt) {
#pragma unroll
      for (int u = 0; u < 4; ++u) {
        const int d = d0 + wm * 64 + mt * 16 + lhi * 4 + u;
        const size_t base = (size_t)i * 262144 + (size_t)d * DDIM;
#pragma unroll
        for (int ct = 0; ct < 4; ++ct) {
          const int f = f0 + wn * 64 + ct * 16 + l15;
          relbf[base + f] = f2bf(rel_w[base + f] + acc[mt][ct][u]);
        }
      }
    }
  }
}

// ---------------------------------------------------------------------------
// memgemm v2: 1024 threads (16 waves), each wave owns 128m x 32n.
#define MGK 262144
#define MGKC 1024
#define MGCHUNK 256
__global__ __launch_bounds__(1024, 4) void memgemm_k(
    const unsigned short* __restrict__ Ag, const float* __restrict__ Bg,
    float* __restrict__ partial) {
  __shared__ unsigned short As[128][40];
  __shared__ unsigned short Bs[32][520];
  const int tid = threadIdx.x;
  const int l = tid & 63, w = tid >> 6;          // w 0..15
  const int l15 = l & 15, lhi = l >> 4;
  const int kbeg = blockIdx.x * MGKC;
  const int arow = tid >> 3, akq = tid & 7;      // A: 4 shorts each
  const int bk = tid >> 5, bnq = (tid & 31) * 16; // B: 16 f32 each
  f32x4 acc[8][2] = {};

  for (int t32 = 0; t32 < MGKC / 32; ++t32) {
    const int kb = kbeg + t32 * 32;
    short4v av = {};
    if (arow < MMEM)
      av = *(const short4v*)(Ag + (size_t)arow * MGK + kb + akq * 4);
    float4 bv[4];
    const float* bp = Bg + (size_t)(kb + bk) * DDIM + bnq;
#pragma unroll
    for (int u = 0; u < 4; ++u) bv[u] = *(const float4*)(bp + 4 * u);
    __syncthreads();
    *(short4v*)&As[arow][akq * 4] = av;
#pragma unroll
    for (int u = 0; u < 2; ++u) {
      short8v pb;
      pb[0] = (short)f2bf(bv[2*u].x);   pb[1] = (short)f2bf(bv[2*u].y);
      pb[2] = (short)f2bf(bv[2*u].z);   pb[3] = (short)f2bf(bv[2*u].w);
      pb[4] = (short)f2bf(bv[2*u+1].x); pb[5] = (short)f2bf(bv[2*u+1].y);
      pb[6] = (short)f2bf(bv[2*u+1].z); pb[7] = (short)f2bf(bv[2*u+1].w);
      *(short8v*)&Bs[bk][bnq + u * 8] = pb;
    }
    __syncthreads();
    union { short8v v; unsigned short u[8]; } bf0, bf1;
    const int nn0 = w * 32 + l15, nn1 = w * 32 + 16 + l15;
#pragma unroll
    for (int j = 0; j < 8; ++j) {
      bf0.u[j] = Bs[lhi * 8 + j][nn0];
      bf1.u[j] = Bs[lhi * 8 + j][nn1];
    }
#pragma unroll
    for (int mt = 0; mt < 8; ++mt) {
      short8v af = *(const short8v*)&As[mt * 16 + l15][lhi * 8];
      acc[mt][0] = __builtin_amdgcn_mfma_f32_16x16x32_bf16(af, bf0.v, acc[mt][0], 0, 0, 0);
      acc[mt][1] = __builtin_amdgcn_mfma_f32_16x16x32_bf16(af, bf1.v, acc[mt][1], 0, 0, 0);
    }
  }

  float* pw = partial + (size_t)blockIdx.x * (MMEM * DDIM);
#pragma unroll
  for (int mt = 0; mt < 8; ++mt) {
    const int r0 = mt * 16 + lhi * 4;
#pragma unroll
    for (int r = 0; r < 4; ++r) {
      const int row = r0 + r;
      if (row < MMEM) {
        pw[(size_t)row * DDIM + w * 32 + l15]      = acc[mt][0][r];
        pw[(size_t)row * DDIM + w * 32 + 16 + l15] = acc[mt][1][r];
      }
    }
  }
}

// Fused reduce(256 partials) + br1 + l2norm -> mnbf (100x512) and mnTbf (512x100)
__global__ __launch_bounds__(512) void reduce_mn_k(
    const float* __restrict__ partial, const float* __restrict__ br1,
    unsigned short* __restrict__ mnbf, unsigned short* __restrict__ mnTbf) {
  __shared__ float r1[8];
  const int i = blockIdx.x, t = threadIdx.x;
  float a = br1[t];
  const float* p = partial + (size_t)i * DDIM + t;
  for (int z = 0; z < MGCHUNK; ++z) a += p[(size_t)z * (MMEM * DDIM)];
  float q = a * a;
#pragma unroll
  for (int o = 32; o; o >>= 1) q += __shfl_xor(q, o, 64);
  if ((t & 63) == 0) r1[t >> 6] = q;
  __syncthreads();
  q = 0.f;
#pragma unroll
  for (int j = 0; j < 8; ++j) q += r1[j];
  float inv = 1.f / fmaxf(sqrtf(q), 1e-12f);
  unsigned short hv = f2bf(a * inv);
  mnbf[(size_t)i * DDIM + t] = hv;
  mnTbf[(size_t)t * MMEM + i] = hv;
}

// ---------------------------------------------------------------------------
// Row softmax over first MMEM cols (f32 in, bf16 out).
__global__ __launch_bounds__(256) void softmax_bf_k(const float* __restrict__ x,
                                                    unsigned short* __restrict__ o,
                                                    int nrows, int ldi, int ldo) {
  int wid = threadIdx.x >> 6;
  int lane = threadIdx.x & 63;
  int row = blockIdx.x * 4 + wid;
  if (row >= nrows) return;
  const float* xr = x + (size_t)row * ldi;
  float v0 = xr[lane];
  bool has1 = (lane + 64) < MMEM;
  float v1 = has1 ? xr[lane + 64] : -3.4e38f;
  float m = fmaxf(v0, v1);
#pragma unroll
  for (int off = 32; off; off >>= 1) m = fmaxf(m, __shfl_xor(m, off, 64));
  float e0 = expf(v0 - m);
  float e1 = has1 ? expf(v1 - m) : 0.f;
  float s = e0 + e1;
#pragma unroll
  for (int off = 32; off; off >>= 1) s += __shfl_xor(s, off, 64);
  float inv = 1.f / s;
  unsigned short* orow = o + (size_t)row * ldo;
  orow[lane] = f2bf(e0 * inv);
  if (has1) orow[lane + 64] = f2bf(e1 * inv);
}

__global__ __launch_bounds__(512) void colsum_bf_k(const unsigned short* __restrict__ A,
                                                   float* __restrict__ out) {
  int d = threadIdx.x;
  int r0 = blockIdx.x * 512;
  float a = 0.f;
  for (int r = 0; r < 512; ++r) a += bf2f(A[(size_t)(r0 + r) * DDIM + d]);
  atomicAdd(&out[d], a);
}

__global__ __launch_bounds__(256) void ip4sum_k(const float* __restrict__ S,
                                                const float* __restrict__ rel_w,
                                                float* __restrict__ out) {
  __shared__ float sv[128];
  int r0 = blockIdx.x * 128;
  int tid = threadIdx.x;
  if (tid < 128) sv[tid] = S[r0 + tid];
  __syncthreads();
  float a0 = 0.f, a1 = 0.f;
  for (int r = 0; r < 128; ++r) {
    const float* row = rel_w + (size_t)(r0 + r) * DDIM;
    float s = sv[r];
    a0 = fmaf(s, row[tid], a0);
    a1 = fmaf(s, row[tid + 256], a1);
  }
  atomicAdd(&out[tid], a0);
  atomicAdd(&out[tid + 256], a1);
}

// itembf = bf16(item(ip1^T ip1, atomically built) + item_w + s4 x s2)
__global__ __launch_bounds__(256) void assemble_item_k(
    const float* __restrict__ item, const float* __restrict__ item_w,
    const float* __restrict__ s4, const float* __restrict__ s2,
    unsigned short* __restrict__ itembf) {
  int idx = blockIdx.x * 256 + threadIdx.x;
  int d = idx >> 9, f = idx & 511;
  itembf[idx] = f2bf(item[idx] + item_w[idx] + s4[d] * s2[f]);
}

// LayerNorm(len 300, eps=512) + direct scatter into qm/km/vm (M x D each)
__global__ __launch_bounds__(256) void ln300_k(const float* __restrict__ x,
                                               const float* __restrict__ g,
                                               const float* __restrict__ bb,
                                               float* __restrict__ qm,
                                               float* __restrict__ km,
                                               float* __restrict__ vm) {
  __shared__ float r1[4], r2[4];
  int row = blockIdx.x, tid = threadIdx.x;
  const float* xr = x + (size_t)row * QKVW;
  float v1 = xr[tid];
  float v2 = (tid + 256 < QKVW) ? xr[tid + 256] : 0.f;
  float s = v1 + v2, q = v1 * v1 + v2 * v2;
#pragma unroll
  for (int o = 32; o; o >>= 1) { s += __shfl_xor(s, o, 64); q += __shfl_xor(q, o, 64); }
  if ((tid & 63) == 0) { r1[tid >> 6] = s; r2[tid >> 6] = q; }
  __syncthreads();
  s = r1[0] + r1[1] + r1[2] + r1[3];
  q = r2[0] + r2[1] + r2[2] + r2[3];
  float mean = s * (1.f / 300.f);
  float var = q * (1.f / 300.f) - mean * mean;
  float inv = rsqrtf(var + 512.0f);
  float y1 = (v1 - mean) * inv * g[tid] + bb[tid];
  int j = tid;
  if (j < 100)      qm[(size_t)j * DDIM + row] = y1;
  else if (j < 200) km[(size_t)(j - 100) * DDIM + row] = y1;
  else              vm[(size_t)(j - 200) * DDIM + row] = y1;
  if (tid + 256 < QKVW) {
    float y2 = (v2 - mean) * inv * g[tid + 256] + bb[tid + 256];
    vm[(size_t)(tid + 56) * DDIM + row] = y2;   // j2-200 = tid+56
  }
}

__global__ void write_mf_k(const float* __restrict__ mf, float* __restrict__ out) {
  __shared__ float tile[32][33];
  int b = blockIdx.z, hw0 = blockIdx.x * 32, c0 = blockIdx.y * 32;
  int tx = threadIdx.x, ty = threadIdx.y;
#pragma unroll
  for (int i = 0; i < 32; i += 8)
    tile[ty + i][tx] = mf[((size_t)b * HWSZ + hw0 + ty + i) * DDIM + c0 + tx];
  __syncthreads();
#pragma unroll
  for (int i = 0; i < 32; i += 8)
    out[(size_t)b * 4194304 + (size_t)(512 + c0 + ty + i) * HWSZ + hw0 + tx] =
        tile[tx][ty + i];
}

// ---------------------------------------------------------------------------
extern "C" void kernel_launch(void* const* d_in, const int* in_sizes, int n_in,
                              void* d_out, int out_size, void* d_ws, size_t ws_size,
                              hipStream_t stream) {
  (void)in_sizes; (void)n_in; (void)out_size; (void)ws_size;
  const float* fea    = (const float*)d_in[0];
  const float* item_w = (const float*)d_in[1];
  const float* rel_w  = (const float*)d_in[2];
  const float* W1     = (const float*)d_in[3];
  const float* W2     = (const float*)d_in[5];
  const float* W3     = (const float*)d_in[7];
  const float* b1     = (const float*)d_in[4];
  const float* b2     = (const float*)d_in[6];
  const float* b3     = (const float*)d_in[8];
  const float* Wqkv   = (const float*)d_in[9];
  const float* bqkv   = (const float*)d_in[10];
  const float* ln_g   = (const float*)d_in[11];
  const float* ln_b   = (const float*)d_in[12];
  const float* Wr1    = (const float*)d_in[13];
  const float* br1    = (const float*)d_in[14];
  float* out = (float*)d_out;
  float* ws = (float*)d_ws;

  // f32 region
  float* ip3     = ws;                         // 1,638,400
  float* addr    = ip3     + 1638400;          // 2,097,152 (ld 128)
  float* mf      = addr    + 2097152;          // 8,388,608
  float* partial = mf      + 8388608;          // 13,107,200
  float* S       = partial + 13107200;         // 51,200  (zeroed)
  float* ip4sum  = S       + 51200;            // 512     (zeroed)
  float* ip2sum  = ip4sum  + 512;              // 512     (zeroed)
  float* item    = ip2sum  + 512;              // 262,144 (zeroed)
  float* qkv     = item    + 262144;           // 153,600
  float* qm      = qkv     + 153600;           // 51,200
  float* km      = qm      + 51200;            // 51,200
  float* vm      = km      + 51200;            // 51,200
  // u16 region
  unsigned short* u16base = (unsigned short*)(vm + 51200);
  unsigned short* qnbf   = u16base;                 // 8,388,608
  unsigned short* ip1bf  = qnbf   + 8388608;        // 8,388,608
  unsigned short* ip2bf  = ip1bf  + 8388608;        // 8,388,608
  unsigned short* ip3bf  = ip2bf  + 8388608;        // 1,638,400
  unsigned short* addrbf = ip3bf  + 1638400;        // 2,097,152 (ld 128)
  unsigned short* relbf  = addrbf + 2097152;        // 26,214,400
  unsigned short* itembf = relbf  + 26214400;       // 262,144
  unsigned short* mnbf   = itembf + 262144;         // 51,200
  unsigned short* mnTbf  = mnbf   + 51200;          // 51,200
  unsigned short* W1bf   = mnTbf  + 51200;          // 262,144
  unsigned short* W2bf   = W1bf   + 262144;         // 262,144
  unsigned short* W3bf   = W2bf   + 262144;         // 51,200
  unsigned short* Wqbf   = W3bf   + 51200;          // 153,600

  // zero atomic targets: S, ip4sum, ip2sum, item (contiguous)
  hipMemsetAsync(S, 0, (size_t)(51200 + 512 + 512 + 262144) * sizeof(float), stream);

  // 0) weights -> bf16
  cvtw_k<<<2848, 256, 0, stream>>>(W1, W2, W3, Wqkv, W1bf, W2bf, W3bf, Wqbf);

  // 1) fused: fea -> out[:, :512] copy + qnbf (l2-normalized tokens, bf16)
  feat_k<<<512, 256, 0, stream>>>(fea, qnbf, out);

  // 2) ip1/ip2 (bf16 out), ip3 (f32) + softmax -> ip3bf
  gemm_bf16_k<true><<<dim3(4, 128), 256, 0, stream>>>(
      qnbf, W1bf, b1, ip1bf, NTOK, DDIM, DDIM, DDIM, DDIM, DDIM);
  gemm_bf16_k<true><<<dim3(4, 128), 256, 0, stream>>>(
      qnbf, W2bf, b2, ip2bf, NTOK, DDIM, DDIM, DDIM, DDIM, DDIM);
  gemm_bf16_k<false><<<dim3(1, 128), 256, 0, stream>>>(
      qnbf, W3bf, b3, ip3, NTOK, MMEM, DDIM, DDIM, MMEM, MMEM);
  softmax_bf_k<<<4096, 256, 0, stream>>>(ip3, ip3bf, NTOK, MMEM, MMEM);

  // 3) item = ip1^T@ip1, S = ip3^T@ip2, colsum, ip4sum
  atb_bf16_k<<<dim3(4, 4, 16), 256, 0, stream>>>(
      ip1bf, ip1bf, item, DDIM, DDIM, NTOK, DDIM, DDIM, DDIM, 1024);
  atb_bf16_k<<<dim3(4, 1, 16), 256, 0, stream>>>(
      ip3bf, ip2bf, S, MMEM, DDIM, NTOK, MMEM, DDIM, DDIM, 1024);
  colsum_bf_k<<<32, 512, 0, stream>>>(ip2bf, ip2sum);
  ip4sum_k<<<400, 256, 0, stream>>>(S, rel_w, ip4sum);

  // 4) itembf = bf16(item + item_w + outer(ip4sum, ip2sum))
  assemble_item_k<<<1024, 256, 0, stream>>>(item, item_w, ip4sum, ip2sum, itembf);

  // 5) qkv = itembf@Wqbf + bqkv; LN(eps=512) + split
  gemm_bf16_k<false><<<dim3(3, 4), 256, 0, stream>>>(
      itembf, Wqbf, bqkv, qkv, DDIM, QKVW, DDIM, DDIM, QKVW, QKVW);
  ln300_k<<<512, 256, 0, stream>>>(qkv, ln_g, ln_b, qm, km, vm);

  // 6) relbf = bf16(rel_w + einsum(tanh(q*k), v))
  rel0_mfma_k<<<dim3(4, MMEM), 256, 0, stream>>>(qm, km, vm, rel_w, relbf);

  // 7) memory = relbf @ Wr1; fused reduce + l2norm -> mnbf/mnTbf
  memgemm_k<<<dim3(MGCHUNK), 1024, 0, stream>>>(relbf, Wr1, partial);
  reduce_mn_k<<<MMEM, 512, 0, stream>>>(partial, br1, mnbf, mnTbf);

  // 8) addr = softmax(qnbf@mnTbf) -> addrbf; mf = addrbf@mnbf
  gemm_bf16_k<false><<<dim3(1, 128), 256, 0, stream>>>(
      qnbf, mnTbf, nullptr, addr, NTOK, MMEM, DDIM, DDIM, MMEM, 128);
  softmax_bf_k<<<4096, 256, 0, stream>>>(addr, addrbf, NTOK, 128, 128);
  gemm_bf16_k<false><<<dim3(4, 128), 256, 0, stream>>>(
      addrbf, mnbf, nullptr, mf, NTOK, DDIM, MMEM, 128, DDIM, DDIM);

  // 9) out second half: mf^T
  write_mf_k<<<dim3(128, 16, 4), dim3(32, 8), 0, stream>>>(mf, out);
}